// Round 4
// baseline (530.721 us; speedup 1.0000x reference)
//
#include <hip/hip_runtime.h>
#include <stdint.h>

typedef unsigned short u16;
typedef __bf16 bf16x8 __attribute__((ext_vector_type(8)));
typedef float f32x4 __attribute__((ext_vector_type(4)));
typedef unsigned int u32x4 __attribute__((ext_vector_type(4)));

typedef __attribute__((address_space(3))) void LDSV;
typedef __attribute__((address_space(1))) void GLV;

#define S_LEN 2048

__device__ __forceinline__ float bf2f(u16 u) {
  union { unsigned int i; float f; } v; v.i = ((unsigned int)u) << 16; return v.f;
}
__device__ __forceinline__ u16 f2bf(float f) {
  union { float f; unsigned int i; } v; v.f = f;
  unsigned int x = v.i;
  return (u16)((x + 0x7fffu + ((x >> 16) & 1u)) >> 16);
}
__device__ __forceinline__ unsigned long long pack4(float4 v) {
  return (unsigned long long)f2bf(v.x)
       | ((unsigned long long)f2bf(v.y) << 16)
       | ((unsigned long long)f2bf(v.z) << 32)
       | ((unsigned long long)f2bf(v.w) << 48);
}

// ---------------- all casts in one dispatch ----------------
// seg5 = wkv_a pad: logical 640x2048, rows >= 576 are zero.
__global__ __launch_bounds__(256) void cast_all(
    const float* __restrict__ s0, u16* __restrict__ d0, long e0,
    const float* __restrict__ s1, u16* __restrict__ d1, long e1,
    const float* __restrict__ s2, u16* __restrict__ d2, long e2,
    const float* __restrict__ s3, u16* __restrict__ d3, long e3,
    const float* __restrict__ s4, u16* __restrict__ d4, long e4,
    const float* __restrict__ s5, u16* __restrict__ d5, long e5) {
  long i = (long)blockIdx.x * 256 + threadIdx.x;
  const float* src; u16* dst; long base; bool pad = false;
  if (i < e0)      { src = s0; dst = d0; base = 0; }
  else if (i < e1) { src = s1; dst = d1; base = e0; }
  else if (i < e2) { src = s2; dst = d2; base = e1; }
  else if (i < e3) { src = s3; dst = d3; base = e2; }
  else if (i < e4) { src = s4; dst = d4; base = e3; }
  else if (i < e5) { src = s5; dst = d5; base = e4; pad = true; }
  else return;
  long li = i - base;
  long elem0 = li * 4;
  unsigned long long r = 0;
  if (!pad || (elem0 >> 11) < 576)
    r = pack4(*(const float4*)(src + elem0));
  ((unsigned long long*)dst)[li] = r;
}

// ---------------- NT GEMM: C[M][N] = A[M][K] * B[N][K]^T ----------------
// 128x128 tile, BK=64, 4 waves, global_load_lds w16, double-buffered LDS,
// ONE barrier per K-step; stage(t+1) issued before compute(t) (T3-min).
// MODE 0: bf16 C[ldc];  MODE 1: f32 C[ldc];  MODE 2: split K-nope/V epilogue.
template <int MODE>
__global__ __launch_bounds__(256) void gemm_nt(const u16* __restrict__ A, int lda,
                                               const u16* __restrict__ B, int ldb,
                                               void* __restrict__ Cv, int ldc,
                                               u16* __restrict__ Vc, int K) {
  __shared__ u16 As[2][128 * 64];
  __shared__ u16 Bs[2][128 * 64];
  const int tid = threadIdx.x;
  const int lane = tid & 63, wid = tid >> 6;
  const int l15 = lane & 15, l4 = lane >> 4;
  const int wr = wid >> 1, wc = wid & 1;
  const long bm = (long)blockIdx.y * 128;
  const long bn = (long)blockIdx.x * 128;

  const int srow = wid * 32 + (lane >> 3);
  const int scol = (lane & 7) * 8;
  const u16* Ag = A + (bm + srow) * (long)lda + scol;
  const u16* Bg = B + (bn + srow) * (long)ldb + scol;

  f32x4 acc[4][4] = {};

  auto stage = [&](int buf, int k0) {
#pragma unroll
    for (int ch = 0; ch < 4; ++ch) {
      __builtin_amdgcn_global_load_lds((const GLV*)(Ag + (long)ch * 8 * lda + k0),
                                       (LDSV*)(&As[buf][wid * 32 * 64 + ch * 512]), 16, 0, 0);
      __builtin_amdgcn_global_load_lds((const GLV*)(Bg + (long)ch * 8 * ldb + k0),
                                       (LDSV*)(&Bs[buf][wid * 32 * 64 + ch * 512]), 16, 0, 0);
    }
  };

  stage(0, 0);
  int cur = 0;
  for (int k0 = 0; k0 < K; k0 += 64) {
    __syncthreads();                       // drains stage(cur); syncs buffer reuse
    if (k0 + 64 < K) stage(cur ^ 1, k0 + 64);  // overlaps with compute below
#pragma unroll
    for (int kk = 0; kk < 2; ++kk) {
      bf16x8 af[4], bfr[4];
#pragma unroll
      for (int m = 0; m < 4; ++m)
        af[m] = *(const bf16x8*)(&As[cur][(wr * 64 + m * 16 + l15) * 64 + (kk * 4 + l4) * 8]);
#pragma unroll
      for (int n = 0; n < 4; ++n)
        bfr[n] = *(const bf16x8*)(&Bs[cur][(wc * 64 + n * 16 + l15) * 64 + (kk * 4 + l4) * 8]);
#pragma unroll
      for (int m = 0; m < 4; ++m)
#pragma unroll
        for (int n = 0; n < 4; ++n)
          acc[m][n] = __builtin_amdgcn_mfma_f32_16x16x32_bf16(af[m], bfr[n], acc[m][n], 0, 0, 0);
    }
    cur ^= 1;
  }
#pragma unroll
  for (int m = 0; m < 4; ++m)
#pragma unroll
    for (int n = 0; n < 4; ++n)
#pragma unroll
      for (int r = 0; r < 4; ++r) {
        long row = bm + wr * 64 + m * 16 + l4 * 4 + r;
        long col = bn + wc * 64 + n * 16 + l15;
        float v = acc[m][n][r];
        if constexpr (MODE == 0) {
          ((u16*)Cv)[row * ldc + col] = f2bf(v);
        } else if constexpr (MODE == 1) {
          ((float*)Cv)[row * ldc + col] = v;
        } else {
          int h = (int)(col >> 8), c = (int)(col & 255);
          if (c < 128)  // k_nope -> Kb [bh][s][192]
            ((u16*)Cv)[(((row >> 11) * 16 + h) * 2048 + (row & 2047)) * 192 + c] = f2bf(v);
          else          // v -> Vc [b*S][h*128+d]
            Vc[row * 2048 + h * 128 + (c - 128)] = f2bf(v);
        }
      }
}

// ---------------- both RMSNorms in one dispatch ----------------
// rows 0..4095: q_a (768 wide, oscale folds softcap scale); 4096..8191: kv (512 wide)
__global__ __launch_bounds__(256) void rmsnorm2_kernel(u16* __restrict__ qakv,
                                                       const float* __restrict__ qw,
                                                       const float* __restrict__ kvw) {
  __shared__ float sred[4];
  const int tid = threadIdx.x;
  const int row = blockIdx.x;
  if (row < 4096) {
    u16* p = qakv + (size_t)row * 1408;
    float x[3];
    float ss = 0.f;
#pragma unroll
    for (int i = 0; i < 3; ++i) { x[i] = bf2f(p[tid + i * 256]); ss += x[i] * x[i]; }
#pragma unroll
    for (int off = 1; off < 64; off <<= 1) ss += __shfl_xor(ss, off);
    if ((tid & 63) == 0) sred[tid >> 6] = ss;
    __syncthreads();
    float tot = sred[0] + sred[1] + sred[2] + sred[3];
    float rs = rsqrtf(tot * (1.0f / 768.0f) + 1e-6f) * 0.0069411711f;  // SCALE*log2e/15
#pragma unroll
    for (int i = 0; i < 3; ++i) p[tid + i * 256] = f2bf(x[i] * rs * qw[tid + i * 256]);
  } else {
    u16* p = qakv + (size_t)(row - 4096) * 1408 + 768;
    float x[2];
    float ss = 0.f;
#pragma unroll
    for (int i = 0; i < 2; ++i) { x[i] = bf2f(p[tid + i * 256]); ss += x[i] * x[i]; }
#pragma unroll
    for (int off = 1; off < 64; off <<= 1) ss += __shfl_xor(ss, off);
    if ((tid & 63) == 0) sred[tid >> 6] = ss;
    __syncthreads();
    float tot = sred[0] + sred[1] + sred[2] + sred[3];
    float rs = rsqrtf(tot * (1.0f / 512.0f) + 1e-6f);
#pragma unroll
    for (int i = 0; i < 2; ++i) p[tid + i * 256] = f2bf(x[i] * rs * kvw[tid + i * 256]);
  }
}

// ---------------- RoPE on q_pe (in-place on q [4096][3072]) ----------------
__global__ __launch_bounds__(256) void rope_q_kernel(u16* __restrict__ q,
                                                     const float* __restrict__ cosb,
                                                     const float* __restrict__ sinb,
                                                     const float* __restrict__ gain) {
  int idx = blockIdx.x * 256 + threadIdx.x;  // B*S*H*32 = 2097152
  int i = idx & 31;
  int h = (idx >> 5) & 15;
  int srow = idx >> 9;
  int s = srow & (S_LEN - 1);
  size_t base = (size_t)srow * 3072 + h * 192 + 128 + 2 * i;
  unsigned int* p = (unsigned int*)(q + base);
  unsigned int v = *p;
  float xe = bf2f((u16)(v & 0xffff)), xo = bf2f((u16)(v >> 16));
  float c = cosb[s * 32 + i], sn = sinb[s * 32 + i];
  float g = gain[h];
  float ye = (xe * c - xo * sn) * g, yo = (xe * sn + xo * c) * g;
  *p = (unsigned int)f2bf(ye) | ((unsigned int)f2bf(yo) << 16);
}

// ---------------- fused RoPE-k + broadcast into Kb cols 128..192 ----------------
__global__ __launch_bounds__(256) void ropek_bcast_kernel(const u16* __restrict__ qakv,
                                                          const float* __restrict__ cosb,
                                                          const float* __restrict__ sinb,
                                                          u16* __restrict__ Kb) {
  int idx = blockIdx.x * 256 + threadIdx.x;  // 4096*32 = 131072
  int i = idx & 31;
  int srow = idx >> 5;               // b*2048 + s
  int s = srow & 2047, b = srow >> 11;
  unsigned int v = *(const unsigned int*)(qakv + (size_t)srow * 1408 + 1280 + 2 * i);
  float xe = bf2f((u16)(v & 0xffff)), xo = bf2f((u16)(v >> 16));
  float c = cosb[s * 32 + i], sn = sinb[s * 32 + i];
  unsigned int rr = (unsigned int)f2bf(xe * c - xo * sn)
                  | ((unsigned int)f2bf(xe * sn + xo * c) << 16);
  u16* kb = Kb + ((long)b * 16 * 2048 + s) * 192 + 128 + 2 * i;
#pragma unroll
  for (int h = 0; h < 16; ++h)
    *(unsigned int*)(kb + (long)h * 2048 * 192) = rr;
}

// ---------------- V transpose: VT [B*H][128][S] from Vc [B*S][2048] ----------------
__global__ __launch_bounds__(256) void v_transpose_kernel(const u16* __restrict__ Vc,
                                                          u16* __restrict__ VT) {
  __shared__ u16 tile[32][33];
  int bh = blockIdx.z;
  int d0 = blockIdx.y * 32;
  int t0 = blockIdx.x * 32;
  int b = bh >> 4, h = bh & 15;
  int tx = threadIdx.x & 31, ty = threadIdx.x >> 5;
#pragma unroll
  for (int j = 0; j < 4; ++j) {
    int t = ty + j * 8;
    tile[t][tx] = Vc[((long)b * S_LEN + t0 + t) * 2048 + h * 128 + d0 + tx];
  }
  __syncthreads();
#pragma unroll
  for (int j = 0; j < 4; ++j) {
    int d = ty + j * 8;
    VT[((long)bh * 128 + d0 + d) * S_LEN + t0 + tx] = tile[tx][d];
  }
}

// ---------------- fused causal attention + softcap + v-projection removal ----------
// 4 waves / 256 threads, QT=128 (32 q-rows per wave = 2 m-frags), KT=64.
// grid 512 = 2 blocks/CU (barrier overlap between blocks). Fixed softmax ref m=30.
// bh = p&31 pins each bh to one XCD; qt = 15-(p>>5) schedules big tiles first.
__global__ __launch_bounds__(256, 2) void attn_kernel(const u16* __restrict__ Qg,
                                                      const u16* __restrict__ Kg,
                                                      const u16* __restrict__ VTg,
                                                      const u16* __restrict__ Vcg,
                                                      u16* __restrict__ Yg) {
  __shared__ u16 Ks[64 * 192];    // 24KB
  __shared__ u16 VTs[128 * 64];   // 16KB
  __shared__ u16 Ps[128 * 64];    // 16KB

  const int tid = threadIdx.x, lane = tid & 63, wid = tid >> 6;
  const int l15 = lane & 15, l4 = lane >> 4;

  const int p = blockIdx.x;          // 512 blocks
  const int bh = p & 31;             // XCD = bh & 7
  const int qt = 15 - (p >> 5);      // big-first
  const int b = bh >> 4, h = bh & 15;
  const int q0 = qt * 128;
  const int nkt = 2 * qt + 2;

  const u16* Kbh = Kg + (long)bh * S_LEN * 192;
  const u16* Vbh = VTg + (long)bh * 128 * S_LEN;

  int krow[6], kc[6]; u16* ksw[6];
#pragma unroll
  for (int i = 0; i < 6; ++i) {
    int flat = i * 256 + tid;
    krow[i] = flat / 24; kc[i] = flat % 24;
    ksw[i] = &Ks[krow[i] * 192 + ((kc[i] ^ (krow[i] & 7)) * 8)];
  }
  int vrow[4], vc[4]; u16* vsw[4];
#pragma unroll
  for (int i = 0; i < 4; ++i) {
    int flat = i * 256 + tid;
    vrow[i] = flat >> 3; vc[i] = flat & 7;
    vsw[i] = &VTs[vrow[i] * 64 + ((vc[i] ^ (vrow[i] & 7)) * 8)];
  }

  bf16x8 qf[2][6];
#pragma unroll
  for (int mf = 0; mf < 2; ++mf) {
    const u16* qb_ = Qg + ((long)b * S_LEN + q0 + wid * 32 + mf * 16 + l15) * 3072 + h * 192;
#pragma unroll
    for (int f = 0; f < 6; ++f) qf[mf][f] = *(const bf16x8*)(qb_ + f * 32 + 8 * l4);
  }

  f32x4 o[2][8] = {};
  float lsum[2][4] = {};

  u32x4 ka[6], va[4];
#pragma unroll
  for (int i = 0; i < 6; ++i)
    ka[i] = *(const u32x4*)(Kbh + (long)krow[i] * 192 + kc[i] * 8);
#pragma unroll
  for (int i = 0; i < 4; ++i)
    va[i] = *(const u32x4*)(Vbh + (long)vrow[i] * S_LEN + vc[i] * 8);

  for (int it = 0; it < nkt; ++it) {
    __syncthreads();
#pragma unroll
    for (int i = 0; i < 6; ++i) *(u32x4*)ksw[i] = ka[i];
#pragma unroll
    for (int i = 0; i < 4; ++i) *(u32x4*)vsw[i] = va[i];
    __syncthreads();
    if (it + 1 < nkt) {
      int k0n = (it + 1) * 64;
#pragma unroll
      for (int i = 0; i < 6; ++i)
        ka[i] = *(const u32x4*)(Kbh + (long)(k0n + krow[i]) * 192 + kc[i] * 8);
#pragma unroll
      for (int i = 0; i < 4; ++i)
        va[i] = *(const u32x4*)(Vbh + (long)vrow[i] * S_LEN + k0n + vc[i] * 8);
    }

    f32x4 sacc[2][4] = {};
    __builtin_amdgcn_s_setprio(1);
#pragma unroll
    for (int f = 0; f < 6; ++f)
#pragma unroll
      for (int tf = 0; tf < 4; ++tf) {
        int row = tf * 16 + l15;
        bf16x8 kf = *(const bf16x8*)(&Ks[row * 192 + (((f * 4 + l4) ^ (row & 7)) * 8)]);
        sacc[0][tf] = __builtin_amdgcn_mfma_f32_16x16x32_bf16(qf[0][f], kf, sacc[0][tf], 0, 0, 0);
        sacc[1][tf] = __builtin_amdgcn_mfma_f32_16x16x32_bf16(qf[1][f], kf, sacc[1][tf], 0, 0, 0);
      }
    __builtin_amdgcn_s_setprio(0);

    const bool diag = (it * 64 >= q0);
#pragma unroll
    for (int mf = 0; mf < 2; ++mf)
#pragma unroll
      for (int tf = 0; tf < 4; ++tf)
#pragma unroll
        for (int r = 0; r < 4; ++r) {
          // q pre-scaled: p = exp2(-60*log2e / (exp2(s)+1))
          float u = __builtin_amdgcn_exp2f(sacc[mf][tf][r]);
          float pe = __builtin_amdgcn_exp2f(-86.56170245333781f *
                                            __builtin_amdgcn_rcpf(u + 1.0f));
          if (diag && (it * 64 + tf * 16 + l15 > q0 + wid * 32 + mf * 16 + l4 * 4 + r)) pe = 0.f;
          lsum[mf][r] += pe;
          int prow = wid * 32 + mf * 16 + l4 * 4 + r, col = tf * 16 + l15;
          Ps[prow * 64 + (((col >> 3) ^ (prow & 7)) * 8) + (col & 7)] = f2bf(pe);
        }

    __builtin_amdgcn_s_setprio(1);
#pragma unroll
    for (int mf = 0; mf < 2; ++mf) {
      const int prow2 = wid * 32 + mf * 16 + l15;
#pragma unroll
      for (int kk = 0; kk < 2; ++kk) {
        bf16x8 pf = *(const bf16x8*)(&Ps[prow2 * 64 + (((kk * 4 + l4) ^ (prow2 & 7)) * 8)]);
#pragma unroll
        for (int nf = 0; nf < 8; ++nf) {
          int vr = nf * 16 + l15;
          bf16x8 vf = *(const bf16x8*)(&VTs[vr * 64 + (((kk * 4 + l4) ^ (vr & 7)) * 8)]);
          o[mf][nf] = __builtin_amdgcn_mfma_f32_16x16x32_bf16(pf, vf, o[mf][nf], 0, 0, 0);
        }
      }
    }
    __builtin_amdgcn_s_setprio(0);
  }

#pragma unroll
  for (int mf = 0; mf < 2; ++mf) {
    float inv[4];
#pragma unroll
    for (int r = 0; r < 4; ++r) {
      float s = lsum[mf][r];
      s += __shfl_xor(s, 1); s += __shfl_xor(s, 2);
      s += __shfl_xor(s, 4); s += __shfl_xor(s, 8);
      inv[r] = __builtin_amdgcn_rcpf(s);
    }
    // fused v-projection removal: y -= (y.v / max(|v|^2,eps)) v
    float yv[8][4], vvv[8][4];
    float ssum[4] = {0.f, 0.f, 0.f, 0.f}, dsum[4] = {0.f, 0.f, 0.f, 0.f};
    const u16* vb = Vcg + ((long)b * S_LEN + q0 + wid * 32 + mf * 16) * 2048 + h * 128;
#pragma unroll
    for (int nf = 0; nf < 8; ++nf)
#pragma unroll
      for (int r = 0; r < 4; ++r) {
        float vv = bf2f(vb[(l4 * 4 + r) * 2048 + nf * 16 + l15]);
        float y = o[mf][nf][r] * inv[r];
        vvv[nf][r] = vv; yv[nf][r] = y;
        ssum[r] += vv * vv; dsum[r] += y * vv;
      }
#pragma unroll
    for (int r = 0; r < 4; ++r) {
      ssum[r] += __shfl_xor(ssum[r], 1); ssum[r] += __shfl_xor(ssum[r], 2);
      ssum[r] += __shfl_xor(ssum[r], 4); ssum[r] += __shfl_xor(ssum[r], 8);
      dsum[r] += __shfl_xor(dsum[r], 1); dsum[r] += __shfl_xor(dsum[r], 2);
      dsum[r] += __shfl_xor(dsum[r], 4); dsum[r] += __shfl_xor(dsum[r], 8);
      dsum[r] *= __builtin_amdgcn_rcpf(fmaxf(ssum[r], 1e-12f));
    }
#pragma unroll
    for (int nf = 0; nf < 8; ++nf)
#pragma unroll
      for (int r = 0; r < 4; ++r) {
        long row = (long)b * S_LEN + q0 + wid * 32 + mf * 16 + l4 * 4 + r;
        Yg[row * 2048 + h * 128 + nf * 16 + l15] = f2bf(yv[nf][r] - dsum[r] * vvv[nf][r]);
      }
  }
}

extern "C" void kernel_launch(void* const* d_in, const int* in_sizes, int n_in,
                              void* d_out, int out_size, void* d_ws, size_t ws_size,
                              hipStream_t stream) {
  const float* x       = (const float*)d_in[0];
  const float* wq_a    = (const float*)d_in[1];
  const float* q_norm  = (const float*)d_in[2];
  const float* wq_b    = (const float*)d_in[3];
  const float* q_gain  = (const float*)d_in[4];
  const float* wkv_a   = (const float*)d_in[5];
  const float* kv_norm = (const float*)d_in[6];
  const float* wkv_b   = (const float*)d_in[7];
  const float* wo      = (const float*)d_in[8];
  const float* fcos    = (const float*)d_in[9];
  const float* fsin    = (const float*)d_in[10];
  float* out = (float*)d_out;

  char* ws = (char*)d_ws;
  size_t off = 0;
  auto alloc = [&](size_t bytes) {
    char* pp = ws + off;
    off += (bytes + 255) & ~(size_t)255;
    return pp;
  };
  const long M = 4096;  // B*S
  u16* xb    = (u16*)alloc(M * 2048 * 2);
  u16* wcomb = (u16*)alloc(1408L * 2048 * 2);  // [wq_a(768); wkv_a(576)+pad(64)]
  u16* wqbb  = (u16*)alloc(3072L * 768 * 2);
  u16* wkvbb = (u16*)alloc(4096L * 512 * 2);
  u16* wob   = (u16*)alloc(2048L * 2048 * 2);
  u16* qakv  = (u16*)alloc(M * 1408 * 2);      // [qa(768) | kv(512) | kpe(64) | pad(64)]
  u16* qb    = (u16*)alloc(M * 3072 * 2);
  u16* Kb    = (u16*)alloc(32L * 2048 * 192 * 2);
  u16* Vc    = (u16*)alloc(M * 2048 * 2);
  u16* VTb   = (u16*)alloc(32L * 128 * 2048 * 2);
  u16* Yb    = (u16*)alloc(M * 2048 * 2);

  // one cast dispatch; cumulative n4 boundaries
  const long n4_x = 2097152, n4_wqa = 393216, n4_wqb = 589824,
             n4_wkvb = 524288, n4_wo = 1048576, n4_wkvap = 327680;
  long e0 = n4_x, e1 = e0 + n4_wqa, e2 = e1 + n4_wqb, e3 = e2 + n4_wkvb,
       e4 = e3 + n4_wo, e5 = e4 + n4_wkvap;
  cast_all<<<(int)(e5 / 256), 256, 0, stream>>>(
      x, xb, e0, wq_a, wcomb, e1, wq_b, wqbb, e2, wkv_b, wkvbb, e3,
      wo, wob, e4, wkv_a, wcomb + 768L * 2048, e5);

  // fused: [q_a | kv_full] = x @ [wq_a; wkv_a]^T   (N=1408)
  gemm_nt<0><<<dim3(11, 32), 256, 0, stream>>>(xb, 2048, wcomb, 2048, qakv, 1408, nullptr, 2048);
  rmsnorm2_kernel<<<8192, 256, 0, stream>>>(qakv, q_norm, kv_norm);
  // q = q_a @ wq_b^T
  gemm_nt<0><<<dim3(24, 32), 256, 0, stream>>>(qakv, 1408, wqbb, 768, qb, 3072, nullptr, 768);
  rope_q_kernel<<<2097152 / 256, 256, 0, stream>>>(qb, fcos, fsin, q_gain);
  ropek_bcast_kernel<<<131072 / 256, 256, 0, stream>>>(qakv, fcos, fsin, Kb);
  // kvb = kv @ wkv_b^T, epilogue-split into Kb (k_nope) and Vc (v)
  gemm_nt<2><<<dim3(32, 32), 256, 0, stream>>>(qakv + 768, 1408, wkvbb, 512, Kb, 0, Vc, 512);
  v_transpose_kernel<<<dim3(64, 4, 32), 256, 0, stream>>>(Vc, VTb);
  attn_kernel<<<512, 256, 0, stream>>>(qb, Kb, VTb, Vc, Yb);
  // out = y @ wo^T (f32 out)
  gemm_nt<1><<<dim3(16, 32), 256, 0, stream>>>(Yb, 2048, wob, 2048, out, 2048, nullptr, 2048);
}

// Round 5
// 303.654 us; speedup vs baseline: 1.7478x; 1.7478x over previous
//
#include <hip/hip_runtime.h>
#include <stdint.h>

typedef unsigned short u16;
typedef __bf16 bf16x8 __attribute__((ext_vector_type(8)));
typedef float f32x4 __attribute__((ext_vector_type(4)));
typedef unsigned int u32x4 __attribute__((ext_vector_type(4)));

typedef __attribute__((address_space(3))) void LDSV;
typedef __attribute__((address_space(1))) void GLV;

#define S_LEN 2048

__device__ __forceinline__ float bf2f(u16 u) {
  union { unsigned int i; float f; } v; v.i = ((unsigned int)u) << 16; return v.f;
}
__device__ __forceinline__ u16 f2bf(float f) {
  union { float f; unsigned int i; } v; v.f = f;
  unsigned int x = v.i;
  return (u16)((x + 0x7fffu + ((x >> 16) & 1u)) >> 16);
}
__device__ __forceinline__ unsigned long long pack4(float4 v) {
  return (unsigned long long)f2bf(v.x)
       | ((unsigned long long)f2bf(v.y) << 16)
       | ((unsigned long long)f2bf(v.z) << 32)
       | ((unsigned long long)f2bf(v.w) << 48);
}

// ---------------- all casts in one dispatch ----------------
// seg5 = wkv_a pad: logical 640x2048, rows >= 576 are zero.
__global__ __launch_bounds__(256) void cast_all(
    const float* __restrict__ s0, u16* __restrict__ d0, long e0,
    const float* __restrict__ s1, u16* __restrict__ d1, long e1,
    const float* __restrict__ s2, u16* __restrict__ d2, long e2,
    const float* __restrict__ s3, u16* __restrict__ d3, long e3,
    const float* __restrict__ s4, u16* __restrict__ d4, long e4,
    const float* __restrict__ s5, u16* __restrict__ d5, long e5) {
  long i = (long)blockIdx.x * 256 + threadIdx.x;
  const float* src; u16* dst; long base; bool pad = false;
  if (i < e0)      { src = s0; dst = d0; base = 0; }
  else if (i < e1) { src = s1; dst = d1; base = e0; }
  else if (i < e2) { src = s2; dst = d2; base = e1; }
  else if (i < e3) { src = s3; dst = d3; base = e2; }
  else if (i < e4) { src = s4; dst = d4; base = e3; }
  else if (i < e5) { src = s5; dst = d5; base = e4; pad = true; }
  else return;
  long li = i - base;
  long elem0 = li * 4;
  unsigned long long r = 0;
  if (!pad || (elem0 >> 11) < 576)
    r = pack4(*(const float4*)(src + elem0));
  ((unsigned long long*)dst)[li] = r;
}

// ---------------- NT GEMM: C[M][N] = A[M][K] * B[N][K]^T ----------------
// m97 structure: 128x128 tile, BK=64, 4 waves, global_load_lds w16, linear LDS,
// single buffer (32KB -> high occupancy), 2 barriers per K-step.
// MODE 0: bf16 C[ldc];  MODE 1: f32 C[ldc];  MODE 2: split K-nope/V epilogue.
template <int MODE>
__global__ __launch_bounds__(256) void gemm_nt(const u16* __restrict__ A, int lda,
                                               const u16* __restrict__ B, int ldb,
                                               void* __restrict__ Cv, int ldc,
                                               u16* __restrict__ Vc, int K) {
  __shared__ u16 As[128 * 64];
  __shared__ u16 Bs[128 * 64];
  const int tid = threadIdx.x;
  const int lane = tid & 63, wid = tid >> 6;
  const int l15 = lane & 15, l4 = lane >> 4;
  const int wr = wid >> 1, wc = wid & 1;
  const long bm = (long)blockIdx.y * 128;
  const long bn = (long)blockIdx.x * 128;

  const int srow = wid * 32 + (lane >> 3);
  const int scol = (lane & 7) * 8;
  const u16* Ag = A + (bm + srow) * (long)lda + scol;
  const u16* Bg = B + (bn + srow) * (long)ldb + scol;
  u16* AsW = &As[wid * 32 * 64];
  u16* BsW = &Bs[wid * 32 * 64];

  f32x4 acc[4][4] = {};

  for (int k0 = 0; k0 < K; k0 += 64) {
    __syncthreads();
#pragma unroll
    for (int ch = 0; ch < 4; ++ch) {
      __builtin_amdgcn_global_load_lds((const GLV*)(Ag + (long)ch * 8 * lda + k0),
                                       (LDSV*)(AsW + ch * 512), 16, 0, 0);
      __builtin_amdgcn_global_load_lds((const GLV*)(Bg + (long)ch * 8 * ldb + k0),
                                       (LDSV*)(BsW + ch * 512), 16, 0, 0);
    }
    __syncthreads();
#pragma unroll
    for (int kk = 0; kk < 2; ++kk) {
      bf16x8 af[4], bfr[4];
#pragma unroll
      for (int m = 0; m < 4; ++m)
        af[m] = *(const bf16x8*)(&As[(wr * 64 + m * 16 + l15) * 64 + (kk * 4 + l4) * 8]);
#pragma unroll
      for (int n = 0; n < 4; ++n)
        bfr[n] = *(const bf16x8*)(&Bs[(wc * 64 + n * 16 + l15) * 64 + (kk * 4 + l4) * 8]);
#pragma unroll
      for (int m = 0; m < 4; ++m)
#pragma unroll
        for (int n = 0; n < 4; ++n)
          acc[m][n] = __builtin_amdgcn_mfma_f32_16x16x32_bf16(af[m], bfr[n], acc[m][n], 0, 0, 0);
    }
  }
#pragma unroll
  for (int m = 0; m < 4; ++m)
#pragma unroll
    for (int n = 0; n < 4; ++n)
#pragma unroll
      for (int r = 0; r < 4; ++r) {
        long row = bm + wr * 64 + m * 16 + l4 * 4 + r;
        long col = bn + wc * 64 + n * 16 + l15;
        float v = acc[m][n][r];
        if constexpr (MODE == 0) {
          ((u16*)Cv)[row * ldc + col] = f2bf(v);
        } else if constexpr (MODE == 1) {
          ((float*)Cv)[row * ldc + col] = v;
        } else {
          int h = (int)(col >> 8), c = (int)(col & 255);
          if (c < 128)  // k_nope -> Kb [bh][s][192]
            ((u16*)Cv)[(((row >> 11) * 16 + h) * 2048 + (row & 2047)) * 192 + c] = f2bf(v);
          else          // v -> Vc [b*S][h*128+d]
            Vc[row * 2048 + h * 128 + (c - 128)] = f2bf(v);
        }
      }
}

// ---------------- both RMSNorms in one dispatch ----------------
// rows 0..4095: q_a (768 wide, oscale folds softcap scale); 4096..8191: kv (512 wide)
__global__ __launch_bounds__(256) void rmsnorm2_kernel(u16* __restrict__ qakv,
                                                       const float* __restrict__ qw,
                                                       const float* __restrict__ kvw) {
  __shared__ float sred[4];
  const int tid = threadIdx.x;
  const int row = blockIdx.x;
  if (row < 4096) {
    u16* p = qakv + (size_t)row * 1408;
    float x[3];
    float ss = 0.f;
#pragma unroll
    for (int i = 0; i < 3; ++i) { x[i] = bf2f(p[tid + i * 256]); ss += x[i] * x[i]; }
#pragma unroll
    for (int off = 1; off < 64; off <<= 1) ss += __shfl_xor(ss, off);
    if ((tid & 63) == 0) sred[tid >> 6] = ss;
    __syncthreads();
    float tot = sred[0] + sred[1] + sred[2] + sred[3];
    float rs = rsqrtf(tot * (1.0f / 768.0f) + 1e-6f) * 0.0069411711f;  // SCALE*log2e/15
#pragma unroll
    for (int i = 0; i < 3; ++i) p[tid + i * 256] = f2bf(x[i] * rs * qw[tid + i * 256]);
  } else {
    u16* p = qakv + (size_t)(row - 4096) * 1408 + 768;
    float x[2];
    float ss = 0.f;
#pragma unroll
    for (int i = 0; i < 2; ++i) { x[i] = bf2f(p[tid + i * 256]); ss += x[i] * x[i]; }
#pragma unroll
    for (int off = 1; off < 64; off <<= 1) ss += __shfl_xor(ss, off);
    if ((tid & 63) == 0) sred[tid >> 6] = ss;
    __syncthreads();
    float tot = sred[0] + sred[1] + sred[2] + sred[3];
    float rs = rsqrtf(tot * (1.0f / 512.0f) + 1e-6f);
#pragma unroll
    for (int i = 0; i < 2; ++i) p[tid + i * 256] = f2bf(x[i] * rs * kvw[tid + i * 256]);
  }
}

// ---------------- RoPE on q_pe (in-place on q [4096][3072]) ----------------
__global__ __launch_bounds__(256) void rope_q_kernel(u16* __restrict__ q,
                                                     const float* __restrict__ cosb,
                                                     const float* __restrict__ sinb,
                                                     const float* __restrict__ gain) {
  int idx = blockIdx.x * 256 + threadIdx.x;  // B*S*H*32 = 2097152
  int i = idx & 31;
  int h = (idx >> 5) & 15;
  int srow = idx >> 9;
  int s = srow & (S_LEN - 1);
  size_t base = (size_t)srow * 3072 + h * 192 + 128 + 2 * i;
  unsigned int* p = (unsigned int*)(q + base);
  unsigned int v = *p;
  float xe = bf2f((u16)(v & 0xffff)), xo = bf2f((u16)(v >> 16));
  float c = cosb[s * 32 + i], sn = sinb[s * 32 + i];
  float g = gain[h];
  float ye = (xe * c - xo * sn) * g, yo = (xe * sn + xo * c) * g;
  *p = (unsigned int)f2bf(ye) | ((unsigned int)f2bf(yo) << 16);
}

// ---------------- fused RoPE-k + broadcast into Kb cols 128..192 ----------------
__global__ __launch_bounds__(256) void ropek_bcast_kernel(const u16* __restrict__ qakv,
                                                          const float* __restrict__ cosb,
                                                          const float* __restrict__ sinb,
                                                          u16* __restrict__ Kb) {
  int idx = blockIdx.x * 256 + threadIdx.x;  // 4096*32 = 131072
  int i = idx & 31;
  int srow = idx >> 5;               // b*2048 + s
  int s = srow & 2047, b = srow >> 11;
  unsigned int v = *(const unsigned int*)(qakv + (size_t)srow * 1408 + 1280 + 2 * i);
  float xe = bf2f((u16)(v & 0xffff)), xo = bf2f((u16)(v >> 16));
  float c = cosb[s * 32 + i], sn = sinb[s * 32 + i];
  unsigned int rr = (unsigned int)f2bf(xe * c - xo * sn)
                  | ((unsigned int)f2bf(xe * sn + xo * c) << 16);
  u16* kb = Kb + ((long)b * 16 * 2048 + s) * 192 + 128 + 2 * i;
#pragma unroll
  for (int h = 0; h < 16; ++h)
    *(unsigned int*)(kb + (long)h * 2048 * 192) = rr;
}

// ---------------- V transpose: VT [B*H][128][S] from Vc [B*S][2048] ----------------
__global__ __launch_bounds__(256) void v_transpose_kernel(const u16* __restrict__ Vc,
                                                          u16* __restrict__ VT) {
  __shared__ u16 tile[32][33];
  int bh = blockIdx.z;
  int d0 = blockIdx.y * 32;
  int t0 = blockIdx.x * 32;
  int b = bh >> 4, h = bh & 15;
  int tx = threadIdx.x & 31, ty = threadIdx.x >> 5;
#pragma unroll
  for (int j = 0; j < 4; ++j) {
    int t = ty + j * 8;
    tile[t][tx] = Vc[((long)b * S_LEN + t0 + t) * 2048 + h * 128 + d0 + tx];
  }
  __syncthreads();
#pragma unroll
  for (int j = 0; j < 4; ++j) {
    int d = ty + j * 8;
    VT[((long)bh * 128 + d0 + d) * S_LEN + t0 + tx] = tile[tx][d];
  }
}

// ---------------- fused causal attention + softcap + v-projection removal ----------
// 8 waves, QT=128 (16 q-rows/wave), KT=64. Fixed softmax ref m=30. Paired q-tiles
// (qt,15-qt): 34 k-tiles per block uniformly. XCD swizzle: all 8 blocks of a bh on
// one XCD. Q pre-scaled by SCALE*log2(e)/15 in rmsnorm.
__global__ __launch_bounds__(512, 2) void attn_kernel(const u16* __restrict__ Qg,
                                                      const u16* __restrict__ Kg,
                                                      const u16* __restrict__ VTg,
                                                      const u16* __restrict__ Vcg,
                                                      u16* __restrict__ Yg) {
  __shared__ u16 Ks[64 * 192];    // 24KB
  __shared__ u16 VTs[128 * 64];   // 16KB
  __shared__ u16 Ps[128 * 64];    // 16KB

  const int tid = threadIdx.x, lane = tid & 63, wid = tid >> 6;
  const int l15 = lane & 15, l4 = lane >> 4;

  const int p = blockIdx.x;               // 256 blocks
  const int bh = (p & 7) * 4 + (p >> 6);  // same-bh blocks share an XCD
  const int pair = (p >> 3) & 7;
  const int b = bh >> 4, h = bh & 15;

  const u16* Kbh = Kg + (long)bh * S_LEN * 192;
  const u16* Vbh = VTg + (long)bh * 128 * S_LEN;

  int krow[3], kc[3], vrow[2], vc[2];
  u16* ksw[3]; u16* vsw[2];
#pragma unroll
  for (int i = 0; i < 3; ++i) {
    int flat = i * 512 + tid;
    krow[i] = flat / 24; kc[i] = flat % 24;
    ksw[i] = &Ks[krow[i] * 192 + ((kc[i] ^ (krow[i] & 7)) * 8)];
  }
#pragma unroll
  for (int i = 0; i < 2; ++i) {
    int flat = i * 512 + tid;
    vrow[i] = flat >> 3; vc[i] = flat & 7;
    vsw[i] = &VTs[vrow[i] * 64 + ((vc[i] ^ (vrow[i] & 7)) * 8)];
  }

  for (int seg = 0; seg < 2; ++seg) {
    const int qt = seg ? pair : 15 - pair;
    const int q0 = qt * 128;
    const int nkt = 2 * qt + 2;

    bf16x8 qf[6];
    {
      const u16* qb_ = Qg + ((long)b * S_LEN + q0 + wid * 16 + l15) * 3072 + h * 192;
#pragma unroll
      for (int f = 0; f < 6; ++f) qf[f] = *(const bf16x8*)(qb_ + f * 32 + 8 * l4);
    }

    f32x4 o[8] = {};
    float lsum[4] = {0.f, 0.f, 0.f, 0.f};

    u32x4 ka[3], va[2];
#pragma unroll
    for (int i = 0; i < 3; ++i)
      ka[i] = *(const u32x4*)(Kbh + (long)krow[i] * 192 + kc[i] * 8);
#pragma unroll
    for (int i = 0; i < 2; ++i)
      va[i] = *(const u32x4*)(Vbh + (long)vrow[i] * S_LEN + vc[i] * 8);

    for (int it = 0; it < nkt; ++it) {
      __syncthreads();
#pragma unroll
      for (int i = 0; i < 3; ++i) *(u32x4*)ksw[i] = ka[i];
#pragma unroll
      for (int i = 0; i < 2; ++i) *(u32x4*)vsw[i] = va[i];
      __syncthreads();
      if (it + 1 < nkt) {
        int k0n = (it + 1) * 64;
#pragma unroll
        for (int i = 0; i < 3; ++i)
          ka[i] = *(const u32x4*)(Kbh + (long)(k0n + krow[i]) * 192 + kc[i] * 8);
#pragma unroll
        for (int i = 0; i < 2; ++i)
          va[i] = *(const u32x4*)(Vbh + (long)vrow[i] * S_LEN + k0n + vc[i] * 8);
      }

      f32x4 sacc[4] = {};
      __builtin_amdgcn_s_setprio(1);
#pragma unroll
      for (int f = 0; f < 6; ++f)
#pragma unroll
        for (int tf = 0; tf < 4; ++tf) {
          int row = tf * 16 + l15;
          bf16x8 kf = *(const bf16x8*)(&Ks[row * 192 + (((f * 4 + l4) ^ (row & 7)) * 8)]);
          sacc[tf] = __builtin_amdgcn_mfma_f32_16x16x32_bf16(qf[f], kf, sacc[tf], 0, 0, 0);
        }
      __builtin_amdgcn_s_setprio(0);

      const bool diag = (it * 64 >= q0);
#pragma unroll
      for (int tf = 0; tf < 4; ++tf)
#pragma unroll
        for (int r = 0; r < 4; ++r) {
          // scores pre-scaled: p = exp2(-60*log2e / (exp2(s)+1))
          float u = __builtin_amdgcn_exp2f(sacc[tf][r]);
          float pe = __builtin_amdgcn_exp2f(-86.56170245333781f *
                                            __builtin_amdgcn_rcpf(u + 1.0f));
          if (diag && (it * 64 + tf * 16 + l15 > q0 + wid * 16 + l4 * 4 + r)) pe = 0.f;
          lsum[r] += pe;
          int prow = wid * 16 + l4 * 4 + r, col = tf * 16 + l15;
          Ps[prow * 64 + (((col >> 3) ^ (prow & 7)) * 8) + (col & 7)] = f2bf(pe);
        }

      __builtin_amdgcn_s_setprio(1);
      const int prow2 = wid * 16 + l15;
#pragma unroll
      for (int kk = 0; kk < 2; ++kk) {
        bf16x8 pf = *(const bf16x8*)(&Ps[prow2 * 64 + (((kk * 4 + l4) ^ (prow2 & 7)) * 8)]);
#pragma unroll
        for (int nf = 0; nf < 8; ++nf) {
          int vr = nf * 16 + l15;
          bf16x8 vf = *(const bf16x8*)(&VTs[vr * 64 + (((kk * 4 + l4) ^ (vr & 7)) * 8)]);
          o[nf] = __builtin_amdgcn_mfma_f32_16x16x32_bf16(pf, vf, o[nf], 0, 0, 0);
        }
      }
      __builtin_amdgcn_s_setprio(0);
    }

    float inv[4];
#pragma unroll
    for (int r = 0; r < 4; ++r) {
      float s = lsum[r];
      s += __shfl_xor(s, 1); s += __shfl_xor(s, 2);
      s += __shfl_xor(s, 4); s += __shfl_xor(s, 8);
      inv[r] = __builtin_amdgcn_rcpf(s);
    }

    // fused v-projection removal: y -= (y.v / max(|v|^2,eps)) v
    float yv[8][4], vvv[8][4];
    float ssum[4] = {0.f, 0.f, 0.f, 0.f}, dsum[4] = {0.f, 0.f, 0.f, 0.f};
    const u16* vb = Vcg + ((long)b * S_LEN + q0 + wid * 16) * 2048 + h * 128;
#pragma unroll
    for (int nf = 0; nf < 8; ++nf)
#pragma unroll
      for (int r = 0; r < 4; ++r) {
        float vv = bf2f(vb[(l4 * 4 + r) * 2048 + nf * 16 + l15]);
        float y = o[nf][r] * inv[r];
        vvv[nf][r] = vv; yv[nf][r] = y;
        ssum[r] += vv * vv; dsum[r] += y * vv;
      }
#pragma unroll
    for (int r = 0; r < 4; ++r) {
      ssum[r] += __shfl_xor(ssum[r], 1); ssum[r] += __shfl_xor(ssum[r], 2);
      ssum[r] += __shfl_xor(ssum[r], 4); ssum[r] += __shfl_xor(ssum[r], 8);
      dsum[r] += __shfl_xor(dsum[r], 1); dsum[r] += __shfl_xor(dsum[r], 2);
      dsum[r] += __shfl_xor(dsum[r], 4); dsum[r] += __shfl_xor(dsum[r], 8);
      dsum[r] *= __builtin_amdgcn_rcpf(fmaxf(ssum[r], 1e-12f));
    }
#pragma unroll
    for (int nf = 0; nf < 8; ++nf)
#pragma unroll
      for (int r = 0; r < 4; ++r) {
        long row = (long)b * S_LEN + q0 + wid * 16 + l4 * 4 + r;
        Yg[row * 2048 + h * 128 + nf * 16 + l15] = f2bf(yv[nf][r] - dsum[r] * vvv[nf][r]);
      }
  }
}

extern "C" void kernel_launch(void* const* d_in, const int* in_sizes, int n_in,
                              void* d_out, int out_size, void* d_ws, size_t ws_size,
                              hipStream_t stream) {
  const float* x       = (const float*)d_in[0];
  const float* wq_a    = (const float*)d_in[1];
  const float* q_norm  = (const float*)d_in[2];
  const float* wq_b    = (const float*)d_in[3];
  const float* q_gain  = (const float*)d_in[4];
  const float* wkv_a   = (const float*)d_in[5];
  const float* kv_norm = (const float*)d_in[6];
  const float* wkv_b   = (const float*)d_in[7];
  const float* wo      = (const float*)d_in[8];
  const float* fcos    = (const float*)d_in[9];
  const float* fsin    = (const float*)d_in[10];
  float* out = (float*)d_out;

  char* ws = (char*)d_ws;
  size_t off = 0;
  auto alloc = [&](size_t bytes) {
    char* pp = ws + off;
    off += (bytes + 255) & ~(size_t)255;
    return pp;
  };
  const long M = 4096;  // B*S
  u16* xb    = (u16*)alloc(M * 2048 * 2);
  u16* wcomb = (u16*)alloc(1408L * 2048 * 2);  // [wq_a(768); wkv_a(576)+pad(64)]
  u16* wqbb  = (u16*)alloc(3072L * 768 * 2);
  u16* wkvbb = (u16*)alloc(4096L * 512 * 2);
  u16* wob   = (u16*)alloc(2048L * 2048 * 2);
  u16* qakv  = (u16*)alloc(M * 1408 * 2);      // [qa(768) | kv(512) | kpe(64) | pad(64)]
  u16* qb    = (u16*)alloc(M * 3072 * 2);
  u16* Kb    = (u16*)alloc(32L * 2048 * 192 * 2);
  u16* Vc    = (u16*)alloc(M * 2048 * 2);
  u16* VTb   = (u16*)alloc(32L * 128 * 2048 * 2);
  u16* Yb    = (u16*)alloc(M * 2048 * 2);

  // one cast dispatch; cumulative n4 boundaries
  const long n4_x = 2097152, n4_wqa = 393216, n4_wqb = 589824,
             n4_wkvb = 524288, n4_wo = 1048576, n4_wkvap = 327680;
  long e0 = n4_x, e1 = e0 + n4_wqa, e2 = e1 + n4_wqb, e3 = e2 + n4_wkvb,
       e4 = e3 + n4_wo, e5 = e4 + n4_wkvap;
  cast_all<<<(int)(e5 / 256), 256, 0, stream>>>(
      x, xb, e0, wq_a, wcomb, e1, wq_b, wqbb, e2, wkv_b, wkvbb, e3,
      wo, wob, e4, wkv_a, wcomb + 768L * 2048, e5);

  // fused: [q_a | kv_full] = x @ [wq_a; wkv_a]^T   (N=1408)
  gemm_nt<0><<<dim3(11, 32), 256, 0, stream>>>(xb, 2048, wcomb, 2048, qakv, 1408, nullptr, 2048);
  rmsnorm2_kernel<<<8192, 256, 0, stream>>>(qakv, q_norm, kv_norm);
  // q = q_a @ wq_b^T
  gemm_nt<0><<<dim3(24, 32), 256, 0, stream>>>(qakv, 1408, wqbb, 768, qb, 3072, nullptr, 768);
  rope_q_kernel<<<2097152 / 256, 256, 0, stream>>>(qb, fcos, fsin, q_gain);
  ropek_bcast_kernel<<<131072 / 256, 256, 0, stream>>>(qakv, fcos, fsin, Kb);
  // kvb = kv @ wkv_b^T, epilogue-split into Kb (k_nope) and Vc (v)
  gemm_nt<2><<<dim3(32, 32), 256, 0, stream>>>(qakv + 768, 1408, wkvbb, 512, Kb, 0, Vc, 512);
  v_transpose_kernel<<<dim3(64, 4, 32), 256, 0, stream>>>(Vc, VTb);
  attn_kernel<<<256, 512, 0, stream>>>(qb, Kb, VTb, Vc, Yb);
  // out = y @ wo^T (f32 out)
  gemm_nt<1><<<dim3(16, 32), 256, 0, stream>>>(Yb, 2048, wob, 2048, out, 2048, nullptr, 2048);
}

// Round 6
// 285.975 us; speedup vs baseline: 1.8558x; 1.0618x over previous
//
#include <hip/hip_runtime.h>
#include <stdint.h>

typedef unsigned short u16;
typedef __bf16 bf16x8 __attribute__((ext_vector_type(8)));
typedef float f32x4 __attribute__((ext_vector_type(4)));
typedef unsigned int u32x4 __attribute__((ext_vector_type(4)));
typedef unsigned int u32x2 __attribute__((ext_vector_type(2)));

typedef __attribute__((address_space(3))) void LDSV;
typedef __attribute__((address_space(1))) void GLV;

#define S_LEN 2048

__device__ __forceinline__ float bf2f(u16 u) {
  union { unsigned int i; float f; } v; v.i = ((unsigned int)u) << 16; return v.f;
}
__device__ __forceinline__ u16 f2bf(float f) {
  union { float f; unsigned int i; } v; v.f = f;
  unsigned int x = v.i;
  return (u16)((x + 0x7fffu + ((x >> 16) & 1u)) >> 16);
}
__device__ __forceinline__ unsigned int cvtpk(float lo, float hi) {
  unsigned int r;
  asm("v_cvt_pk_bf16_f32 %0, %1, %2" : "=v"(r) : "v"(lo), "v"(hi));
  return r;
}
__device__ __forceinline__ unsigned long long pack4(float4 v) {
  return (unsigned long long)f2bf(v.x)
       | ((unsigned long long)f2bf(v.y) << 16)
       | ((unsigned long long)f2bf(v.z) << 32)
       | ((unsigned long long)f2bf(v.w) << 48);
}

// ---------------- all casts in one dispatch ----------------
__global__ __launch_bounds__(256) void cast_all(
    const float* __restrict__ s0, u16* __restrict__ d0, long e0,
    const float* __restrict__ s1, u16* __restrict__ d1, long e1,
    const float* __restrict__ s2, u16* __restrict__ d2, long e2,
    const float* __restrict__ s3, u16* __restrict__ d3, long e3,
    const float* __restrict__ s4, u16* __restrict__ d4, long e4,
    const float* __restrict__ s5, u16* __restrict__ d5, long e5) {
  long i = (long)blockIdx.x * 256 + threadIdx.x;
  const float* src; u16* dst; long base; bool pad = false;
  if (i < e0)      { src = s0; dst = d0; base = 0; }
  else if (i < e1) { src = s1; dst = d1; base = e0; }
  else if (i < e2) { src = s2; dst = d2; base = e1; }
  else if (i < e3) { src = s3; dst = d3; base = e2; }
  else if (i < e4) { src = s4; dst = d4; base = e3; }
  else if (i < e5) { src = s5; dst = d5; base = e4; pad = true; }
  else return;
  long li = i - base;
  long elem0 = li * 4;
  unsigned long long r = 0;
  if (!pad || (elem0 >> 11) < 576)
    r = pack4(*(const float4*)(src + elem0));
  ((unsigned long long*)dst)[li] = r;
}

// ---------------- NT GEMM: C[M][N] = A[M][K] * B[N][K]^T ----------------
// m97 structure: 128x128 tile, BK=64, 4 waves, global_load_lds w16, linear LDS.
// MODE 0: bf16 C[ldc];  MODE 1: f32 C[ldc];  MODE 2: split K-nope/V epilogue.
template <int MODE>
__global__ __launch_bounds__(256) void gemm_nt(const u16* __restrict__ A, int lda,
                                               const u16* __restrict__ B, int ldb,
                                               void* __restrict__ Cv, int ldc,
                                               u16* __restrict__ Vc, int K) {
  __shared__ u16 As[128 * 64];
  __shared__ u16 Bs[128 * 64];
  const int tid = threadIdx.x;
  const int lane = tid & 63, wid = tid >> 6;
  const int l15 = lane & 15, l4 = lane >> 4;
  const int wr = wid >> 1, wc = wid & 1;
  const long bm = (long)blockIdx.y * 128;
  const long bn = (long)blockIdx.x * 128;

  const int srow = wid * 32 + (lane >> 3);
  const int scol = (lane & 7) * 8;
  const u16* Ag = A + (bm + srow) * (long)lda + scol;
  const u16* Bg = B + (bn + srow) * (long)ldb + scol;
  u16* AsW = &As[wid * 32 * 64];
  u16* BsW = &Bs[wid * 32 * 64];

  f32x4 acc[4][4] = {};

  for (int k0 = 0; k0 < K; k0 += 64) {
    __syncthreads();
#pragma unroll
    for (int ch = 0; ch < 4; ++ch) {
      __builtin_amdgcn_global_load_lds((const GLV*)(Ag + (long)ch * 8 * lda + k0),
                                       (LDSV*)(AsW + ch * 512), 16, 0, 0);
      __builtin_amdgcn_global_load_lds((const GLV*)(Bg + (long)ch * 8 * ldb + k0),
                                       (LDSV*)(BsW + ch * 512), 16, 0, 0);
    }
    __syncthreads();
#pragma unroll
    for (int kk = 0; kk < 2; ++kk) {
      bf16x8 af[4], bfr[4];
#pragma unroll
      for (int m = 0; m < 4; ++m)
        af[m] = *(const bf16x8*)(&As[(wr * 64 + m * 16 + l15) * 64 + (kk * 4 + l4) * 8]);
#pragma unroll
      for (int n = 0; n < 4; ++n)
        bfr[n] = *(const bf16x8*)(&Bs[(wc * 64 + n * 16 + l15) * 64 + (kk * 4 + l4) * 8]);
#pragma unroll
      for (int m = 0; m < 4; ++m)
#pragma unroll
        for (int n = 0; n < 4; ++n)
          acc[m][n] = __builtin_amdgcn_mfma_f32_16x16x32_bf16(af[m], bfr[n], acc[m][n], 0, 0, 0);
    }
  }
#pragma unroll
  for (int m = 0; m < 4; ++m)
#pragma unroll
    for (int n = 0; n < 4; ++n)
#pragma unroll
      for (int r = 0; r < 4; ++r) {
        long row = bm + wr * 64 + m * 16 + l4 * 4 + r;
        long col = bn + wc * 64 + n * 16 + l15;
        float v = acc[m][n][r];
        if constexpr (MODE == 0) {
          ((u16*)Cv)[row * ldc + col] = f2bf(v);
        } else if constexpr (MODE == 1) {
          ((float*)Cv)[row * ldc + col] = v;
        } else {
          int h = (int)(col >> 8), c = (int)(col & 255);
          if (c < 128)  // k_nope -> KbN [bh][s][128]
            ((u16*)Cv)[(((row >> 11) * 16 + h) * 2048 + (row & 2047)) * 128 + c] = f2bf(v);
          else          // v -> Vc [b*S][h*128+d]
            Vc[row * 2048 + h * 128 + (c - 128)] = f2bf(v);
        }
      }
}

// ---------------- both RMSNorms in one dispatch ----------------
__global__ __launch_bounds__(256) void rmsnorm2_kernel(u16* __restrict__ qakv,
                                                       const float* __restrict__ qw,
                                                       const float* __restrict__ kvw) {
  __shared__ float sred[4];
  const int tid = threadIdx.x;
  const int row = blockIdx.x;
  if (row < 4096) {
    u16* p = qakv + (size_t)row * 1408;
    float x[3];
    float ss = 0.f;
#pragma unroll
    for (int i = 0; i < 3; ++i) { x[i] = bf2f(p[tid + i * 256]); ss += x[i] * x[i]; }
#pragma unroll
    for (int off = 1; off < 64; off <<= 1) ss += __shfl_xor(ss, off);
    if ((tid & 63) == 0) sred[tid >> 6] = ss;
    __syncthreads();
    float tot = sred[0] + sred[1] + sred[2] + sred[3];
    float rs = rsqrtf(tot * (1.0f / 768.0f) + 1e-6f) * 0.0069411711f;  // SCALE*log2e/15
#pragma unroll
    for (int i = 0; i < 3; ++i) p[tid + i * 256] = f2bf(x[i] * rs * qw[tid + i * 256]);
  } else {
    u16* p = qakv + (size_t)(row - 4096) * 1408 + 768;
    float x[2];
    float ss = 0.f;
#pragma unroll
    for (int i = 0; i < 2; ++i) { x[i] = bf2f(p[tid + i * 256]); ss += x[i] * x[i]; }
#pragma unroll
    for (int off = 1; off < 64; off <<= 1) ss += __shfl_xor(ss, off);
    if ((tid & 63) == 0) sred[tid >> 6] = ss;
    __syncthreads();
    float tot = sred[0] + sred[1] + sred[2] + sred[3];
    float rs = rsqrtf(tot * (1.0f / 512.0f) + 1e-6f);
#pragma unroll
    for (int i = 0; i < 2; ++i) p[tid + i * 256] = f2bf(x[i] * rs * kvw[tid + i * 256]);
  }
}

// ---------------- RoPE on q_pe (in-place on q [4096][3072]) ----------------
__global__ __launch_bounds__(256) void rope_q_kernel(u16* __restrict__ q,
                                                     const float* __restrict__ cosb,
                                                     const float* __restrict__ sinb,
                                                     const float* __restrict__ gain) {
  int idx = blockIdx.x * 256 + threadIdx.x;  // B*S*H*32 = 2097152
  int i = idx & 31;
  int h = (idx >> 5) & 15;
  int srow = idx >> 9;
  int s = srow & (S_LEN - 1);
  size_t base = (size_t)srow * 3072 + h * 192 + 128 + 2 * i;
  unsigned int* p = (unsigned int*)(q + base);
  unsigned int v = *p;
  float xe = bf2f((u16)(v & 0xffff)), xo = bf2f((u16)(v >> 16));
  float c = cosb[s * 32 + i], sn = sinb[s * 32 + i];
  float g = gain[h];
  float ye = (xe * c - xo * sn) * g, yo = (xe * sn + xo * c) * g;
  *p = (unsigned int)f2bf(ye) | ((unsigned int)f2bf(yo) << 16);
}

// ---------------- RoPE on k_pe -> compact kpe [b*S][64] ----------------
__global__ __launch_bounds__(256) void ropek_kernel(const u16* __restrict__ qakv,
                                                    const float* __restrict__ cosb,
                                                    const float* __restrict__ sinb,
                                                    u16* __restrict__ kpe) {
  int idx = blockIdx.x * 256 + threadIdx.x;  // 4096*32 = 131072
  int i = idx & 31;
  int srow = idx >> 5;               // b*2048 + s
  int s = srow & 2047;
  unsigned int v = *(const unsigned int*)(qakv + (size_t)srow * 1408 + 1280 + 2 * i);
  float xe = bf2f((u16)(v & 0xffff)), xo = bf2f((u16)(v >> 16));
  float c = cosb[s * 32 + i], sn = sinb[s * 32 + i];
  *(unsigned int*)(kpe + (size_t)srow * 64 + 2 * i) =
      (unsigned int)f2bf(xe * c - xo * sn) | ((unsigned int)f2bf(xe * sn + xo * c) << 16);
}

// ---------------- V transpose: VT [B*H][128][S] from Vc [B*S][2048] ----------------
// 64x64 tiles, u32x4 global loads/stores, scalar LDS via padded tile.
__global__ __launch_bounds__(256) void v_transpose_kernel(const u16* __restrict__ Vc,
                                                          u16* __restrict__ VT) {
  __shared__ u16 tile[64][65];
  int bh = blockIdx.z;
  int d0 = blockIdx.y * 64;
  int t0 = blockIdx.x * 64;
  int b = bh >> 4, h = bh & 15;
#pragma unroll
  for (int i = 0; i < 2; ++i) {
    int flat = i * 256 + threadIdx.x;
    int t = flat >> 3, c = (flat & 7) * 8;
    u32x4 v = *(const u32x4*)(Vc + ((long)b * S_LEN + t0 + t) * 2048 + h * 128 + d0 + c);
    const u16* pv = (const u16*)&v;
#pragma unroll
    for (int j = 0; j < 8; ++j) tile[c + j][t] = pv[j];
  }
  __syncthreads();
#pragma unroll
  for (int i = 0; i < 2; ++i) {
    int flat = i * 256 + threadIdx.x;
    int d = flat >> 3, tc = (flat & 7) * 8;
    u32x4 v;
    u16* pv = (u16*)&v;
#pragma unroll
    for (int j = 0; j < 8; ++j) pv[j] = tile[d][tc + j];
    *(u32x4*)(VT + ((long)bh * 128 + d0 + d) * S_LEN + t0 + tc) = v;
  }
}

// ---------------- fused causal attention + softcap + v-projection removal ----------
// 8 waves, QT=128 (16 q-rows/wave), KT=64. Fixed softmax ref m=30. Paired q-tiles
// (qt,15-qt): 34 k-tiles/block uniformly. XCD swizzle. SWAPPED QK: mfma(K,Q) puts
// P[qrow=l15][kpos=tf*16+l4*4+r] lane-local -> cvt_pk+ds_write_b64 P path.
__global__ __launch_bounds__(512, 2) void attn_kernel(const u16* __restrict__ Qg,
                                                      const u16* __restrict__ KbN,
                                                      const u16* __restrict__ Kpe,
                                                      const u16* __restrict__ VTg,
                                                      const u16* __restrict__ Vcg,
                                                      u16* __restrict__ Yg) {
  __shared__ u16 Ks[64 * 192];    // 24KB  [kpos][0..127 nope | 128..191 pe]
  __shared__ u16 VTs[128 * 64];   // 16KB
  __shared__ u16 Ps[128 * 64];    // 16KB  [qrow][kpos]

  const int tid = threadIdx.x, lane = tid & 63, wid = tid >> 6;
  const int l15 = lane & 15, l4 = lane >> 4;

  const int p = blockIdx.x;               // 256 blocks
  const int bh = (p & 7) * 4 + (p >> 6);  // same-bh blocks share an XCD
  const int pair = (p >> 3) & 7;
  const int b = bh >> 4, h = bh & 15;

  const u16* Kn = KbN + (long)bh * S_LEN * 128;
  const u16* Kp = Kpe + (long)b * S_LEN * 64;
  const u16* Vbh = VTg + (long)bh * 128 * S_LEN;

  // K staging: 3 chunks/thread from two sources (nope 16 chunks, pe 8 chunks per row)
  int krow[3], sst[3];
  const u16* sb[3];
  u16* ksw[3];
#pragma unroll
  for (int i = 0; i < 3; ++i) {
    int flat = i * 512 + tid;
    int r = flat / 24, c = flat % 24;
    krow[i] = r;
    if (c < 16) { sb[i] = Kn + c * 8; sst[i] = 128; }
    else        { sb[i] = Kp + (c - 16) * 8; sst[i] = 64; }
    ksw[i] = &Ks[r * 192 + ((c ^ (r & 7)) * 8)];
  }
  int vrow[2], vc[2];
  u16* vsw[2];
#pragma unroll
  for (int i = 0; i < 2; ++i) {
    int flat = i * 512 + tid;
    vrow[i] = flat >> 3; vc[i] = flat & 7;
    vsw[i] = &VTs[vrow[i] * 64 + ((vc[i] ^ (vrow[i] & 7)) * 8)];
  }

  const int prow = wid * 16 + l15;   // local q-row owned by this lane (qrow space)
  const int pr7 = prow & 7;

  for (int seg = 0; seg < 2; ++seg) {
    const int qt = seg ? pair : 15 - pair;
    const int q0 = qt * 128;
    const int nkt = 2 * qt + 2;

    bf16x8 qf[6];
    {
      const u16* qb_ = Qg + ((long)b * S_LEN + q0 + prow) * 3072 + h * 192;
#pragma unroll
      for (int f = 0; f < 6; ++f) qf[f] = *(const bf16x8*)(qb_ + f * 32 + 8 * l4);
    }

    f32x4 o[8] = {};
    float lsum = 0.f;

    u32x4 ka[3], va[2];
#pragma unroll
    for (int i = 0; i < 3; ++i)
      ka[i] = *(const u32x4*)(sb[i] + (long)krow[i] * sst[i]);
#pragma unroll
    for (int i = 0; i < 2; ++i)
      va[i] = *(const u32x4*)(Vbh + (long)vrow[i] * S_LEN + vc[i] * 8);

    for (int it = 0; it < nkt; ++it) {
      __syncthreads();
#pragma unroll
      for (int i = 0; i < 3; ++i) *(u32x4*)ksw[i] = ka[i];
#pragma unroll
      for (int i = 0; i < 2; ++i) *(u32x4*)vsw[i] = va[i];
      __syncthreads();
      if (it + 1 < nkt) {
        int k0n = (it + 1) * 64;
#pragma unroll
        for (int i = 0; i < 3; ++i)
          ka[i] = *(const u32x4*)(sb[i] + (long)(k0n + krow[i]) * sst[i]);
#pragma unroll
        for (int i = 0; i < 2; ++i)
          va[i] = *(const u32x4*)(Vbh + (long)vrow[i] * S_LEN + k0n + vc[i] * 8);
      }

      // QK^T swapped: sacc[tf] holds S[kpos = it*64+tf*16+l4*4+r][qrow = q0+prow]
      f32x4 sacc[4] = {};
      __builtin_amdgcn_s_setprio(1);
#pragma unroll
      for (int f = 0; f < 6; ++f)
#pragma unroll
        for (int tf = 0; tf < 4; ++tf) {
          int row = tf * 16 + l15;
          bf16x8 kf = *(const bf16x8*)(&Ks[row * 192 + (((f * 4 + l4) ^ (row & 7)) * 8)]);
          sacc[tf] = __builtin_amdgcn_mfma_f32_16x16x32_bf16(kf, qf[f], sacc[tf], 0, 0, 0);
        }
      __builtin_amdgcn_s_setprio(0);

      // softmax with fixed reference (scores pre-scaled in rmsnorm)
#pragma unroll
      for (int tf = 0; tf < 4; ++tf)
#pragma unroll
        for (int r = 0; r < 4; ++r) {
          float u = __builtin_amdgcn_exp2f(sacc[tf][r]);
          sacc[tf][r] = __builtin_amdgcn_exp2f(-86.56170245333781f *
                                               __builtin_amdgcn_rcpf(u + 1.0f));
        }
      if (it * 64 >= q0) {  // causal: kpos > qrow -> 0
        const int dthr = q0 + prow - it * 64 - l4 * 4;
#pragma unroll
        for (int tf = 0; tf < 4; ++tf)
#pragma unroll
          for (int r = 0; r < 4; ++r)
            if (tf * 16 + r > dthr) sacc[tf][r] = 0.f;
      }
#pragma unroll
      for (int tf = 0; tf < 4; ++tf)
#pragma unroll
        for (int r = 0; r < 4; ++r) lsum += sacc[tf][r];

      // P -> LDS: row=prow, cols kpos (consecutive r) -> pack pairs, b64 writes
#pragma unroll
      for (int tf = 0; tf < 4; ++tf) {
        u32x2 w;
        w.x = cvtpk(sacc[tf][0], sacc[tf][1]);
        w.y = cvtpk(sacc[tf][2], sacc[tf][3]);
        int chunk = tf * 2 + (l4 >> 1);
        *(u32x2*)(&Ps[prow * 64 + ((chunk ^ pr7) * 8) + (l4 & 1) * 4]) = w;
      }

      // PV (unchanged): A=P[qrow][k], B=V^T[d][k]
      __builtin_amdgcn_s_setprio(1);
#pragma unroll
      for (int kk = 0; kk < 2; ++kk) {
        bf16x8 pf = *(const bf16x8*)(&Ps[prow * 64 + (((kk * 4 + l4) ^ pr7) * 8)]);
#pragma unroll
        for (int nf = 0; nf < 8; ++nf) {
          int vr = nf * 16 + l15;
          bf16x8 vf = *(const bf16x8*)(&VTs[vr * 64 + (((kk * 4 + l4) ^ (vr & 7)) * 8)]);
          o[nf] = __builtin_amdgcn_mfma_f32_16x16x32_bf16(pf, vf, o[nf], 0, 0, 0);
        }
      }
      __builtin_amdgcn_s_setprio(0);
    }

    // row-sum: lane has partial for qrow=prow over its kpos set; reduce l4 groups
    lsum += __shfl_xor(lsum, 16);
    lsum += __shfl_xor(lsum, 32);
    float inv[4];
#pragma unroll
    for (int r = 0; r < 4; ++r)
      inv[r] = __builtin_amdgcn_rcpf(__shfl(lsum, (wid << 6 & 0) + l4 * 4 + r));

    // fused v-projection removal: y -= (y.v / max(|v|^2,eps)) v
    float yv[8][4], vvv[8][4];
    float ssum[4] = {0.f, 0.f, 0.f, 0.f}, dsum[4] = {0.f, 0.f, 0.f, 0.f};
    const u16* vb = Vcg + ((long)b * S_LEN + q0 + wid * 16) * 2048 + h * 128;
#pragma unroll
    for (int nf = 0; nf < 8; ++nf)
#pragma unroll
      for (int r = 0; r < 4; ++r) {
        float vv = bf2f(vb[(l4 * 4 + r) * 2048 + nf * 16 + l15]);
        float y = o[nf][r] * inv[r];
        vvv[nf][r] = vv; yv[nf][r] = y;
        ssum[r] += vv * vv; dsum[r] += y * vv;
      }
#pragma unroll
    for (int r = 0; r < 4; ++r) {
      ssum[r] += __shfl_xor(ssum[r], 1); ssum[r] += __shfl_xor(ssum[r], 2);
      ssum[r] += __shfl_xor(ssum[r], 4); ssum[r] += __shfl_xor(ssum[r], 8);
      dsum[r] += __shfl_xor(dsum[r], 1); dsum[r] += __shfl_xor(dsum[r], 2);
      dsum[r] += __shfl_xor(dsum[r], 4); dsum[r] += __shfl_xor(dsum[r], 8);
      dsum[r] *= __builtin_amdgcn_rcpf(fmaxf(ssum[r], 1e-12f));
    }
#pragma unroll
    for (int nf = 0; nf < 8; ++nf)
#pragma unroll
      for (int r = 0; r < 4; ++r) {
        long row = (long)b * S_LEN + q0 + wid * 16 + l4 * 4 + r;
        Yg[row * 2048 + h * 128 + nf * 16 + l15] = f2bf(yv[nf][r] - dsum[r] * vvv[nf][r]);
      }
  }
}

extern "C" void kernel_launch(void* const* d_in, const int* in_sizes, int n_in,
                              void* d_out, int out_size, void* d_ws, size_t ws_size,
                              hipStream_t stream) {
  const float* x       = (const float*)d_in[0];
  const float* wq_a    = (const float*)d_in[1];
  const float* q_norm  = (const float*)d_in[2];
  const float* wq_b    = (const float*)d_in[3];
  const float* q_gain  = (const float*)d_in[4];
  const float* wkv_a   = (const float*)d_in[5];
  const float* kv_norm = (const float*)d_in[6];
  const float* wkv_b   = (const float*)d_in[7];
  const float* wo      = (const float*)d_in[8];
  const float* fcos    = (const float*)d_in[9];
  const float* fsin    = (const float*)d_in[10];
  float* out = (float*)d_out;

  char* ws = (char*)d_ws;
  size_t off = 0;
  auto alloc = [&](size_t bytes) {
    char* pp = ws + off;
    off += (bytes + 255) & ~(size_t)255;
    return pp;
  };
  const long M = 4096;  // B*S
  u16* xb    = (u16*)alloc(M * 2048 * 2);
  u16* wcomb = (u16*)alloc(1408L * 2048 * 2);  // [wq_a(768); wkv_a(576)+pad(64)]
  u16* wqbb  = (u16*)alloc(3072L * 768 * 2);
  u16* wkvbb = (u16*)alloc(4096L * 512 * 2);
  u16* wob   = (u16*)alloc(2048L * 2048 * 2);
  u16* qakv  = (u16*)alloc(M * 1408 * 2);      // [qa(768) | kv(512) | kpe(64) | pad(64)]
  u16* qb    = (u16*)alloc(M * 3072 * 2);
  u16* KbN   = (u16*)alloc(32L * 2048 * 128 * 2);  // k_nope [bh][s][128]
  u16* kpe   = (u16*)alloc(M * 64 * 2);            // roped k_pe [b*s][64]
  u16* Vc    = (u16*)alloc(M * 2048 * 2);
  u16* VTb   = (u16*)alloc(32L * 128 * 2048 * 2);
  u16* Yb    = (u16*)alloc(M * 2048 * 2);

  // one cast dispatch; cumulative n4 boundaries
  const long n4_x = 2097152, n4_wqa = 393216, n4_wqb = 589824,
             n4_wkvb = 524288, n4_wo = 1048576, n4_wkvap = 327680;
  long e0 = n4_x, e1 = e0 + n4_wqa, e2 = e1 + n4_wqb, e3 = e2 + n4_wkvb,
       e4 = e3 + n4_wo, e5 = e4 + n4_wkvap;
  cast_all<<<(int)(e5 / 256), 256, 0, stream>>>(
      x, xb, e0, wq_a, wcomb, e1, wq_b, wqbb, e2, wkv_b, wkvbb, e3,
      wo, wob, e4, wkv_a, wcomb + 768L * 2048, e5);

  // fused: [q_a | kv_full] = x @ [wq_a; wkv_a]^T   (N=1408)
  gemm_nt<0><<<dim3(11, 32), 256, 0, stream>>>(xb, 2048, wcomb, 2048, qakv, 1408, nullptr, 2048);
  rmsnorm2_kernel<<<8192, 256, 0, stream>>>(qakv, q_norm, kv_norm);
  // q = q_a @ wq_b^T
  gemm_nt<0><<<dim3(24, 32), 256, 0, stream>>>(qakv, 1408, wqbb, 768, qb, 3072, nullptr, 768);
  rope_q_kernel<<<2097152 / 256, 256, 0, stream>>>(qb, fcos, fsin, q_gain);
  ropek_kernel<<<131072 / 256, 256, 0, stream>>>(qakv, fcos, fsin, kpe);
  // kvb = kv @ wkv_b^T, epilogue-split into KbN (k_nope) and Vc (v)
  gemm_nt<2><<<dim3(32, 32), 256, 0, stream>>>(qakv + 768, 1408, wkvbb, 512, KbN, 0, Vc, 512);
  v_transpose_kernel<<<dim3(32, 2, 32), 256, 0, stream>>>(Vc, VTb);
  attn_kernel<<<256, 512, 0, stream>>>(qb, KbN, kpe, VTb, Vc, Yb);
  // out = y @ wo^T (f32 out)
  gemm_nt<1><<<dim3(16, 32), 256, 0, stream>>>(Yb, 2048, wob, 2048, out, 2048, nullptr, 2048);
}

// Round 7
// 276.671 us; speedup vs baseline: 1.9182x; 1.0336x over previous
//
#include <hip/hip_runtime.h>
#include <stdint.h>

typedef unsigned short u16;
typedef __bf16 bf16x8 __attribute__((ext_vector_type(8)));
typedef float f32x4 __attribute__((ext_vector_type(4)));
typedef unsigned int u32x4 __attribute__((ext_vector_type(4)));
typedef unsigned int u32x2 __attribute__((ext_vector_type(2)));

typedef __attribute__((address_space(3))) void LDSV;
typedef __attribute__((address_space(1))) void GLV;

#define S_LEN 2048

__device__ __forceinline__ float bf2f(u16 u) {
  union { unsigned int i; float f; } v; v.i = ((unsigned int)u) << 16; return v.f;
}
__device__ __forceinline__ u16 f2bf(float f) {
  union { float f; unsigned int i; } v; v.f = f;
  unsigned int x = v.i;
  return (u16)((x + 0x7fffu + ((x >> 16) & 1u)) >> 16);
}
__device__ __forceinline__ unsigned int cvtpk(float lo, float hi) {
  unsigned int r;
  asm("v_cvt_pk_bf16_f32 %0, %1, %2" : "=v"(r) : "v"(lo), "v"(hi));
  return r;
}
__device__ __forceinline__ unsigned long long pack4(float4 v) {
  return (unsigned long long)f2bf(v.x)
       | ((unsigned long long)f2bf(v.y) << 16)
       | ((unsigned long long)f2bf(v.z) << 32)
       | ((unsigned long long)f2bf(v.w) << 48);
}

// ---------------- all casts in one dispatch ----------------
__global__ __launch_bounds__(256) void cast_all(
    const float* __restrict__ s0, u16* __restrict__ d0, long e0,
    const float* __restrict__ s1, u16* __restrict__ d1, long e1,
    const float* __restrict__ s2, u16* __restrict__ d2, long e2,
    const float* __restrict__ s3, u16* __restrict__ d3, long e3,
    const float* __restrict__ s4, u16* __restrict__ d4, long e4,
    const float* __restrict__ s5, u16* __restrict__ d5, long e5) {
  long i = (long)blockIdx.x * 256 + threadIdx.x;
  const float* src; u16* dst; long base; bool pad = false;
  if (i < e0)      { src = s0; dst = d0; base = 0; }
  else if (i < e1) { src = s1; dst = d1; base = e0; }
  else if (i < e2) { src = s2; dst = d2; base = e1; }
  else if (i < e3) { src = s3; dst = d3; base = e2; }
  else if (i < e4) { src = s4; dst = d4; base = e3; }
  else if (i < e5) { src = s5; dst = d5; base = e4; pad = true; }
  else return;
  long li = i - base;
  long elem0 = li * 4;
  unsigned long long r = 0;
  if (!pad || (elem0 >> 11) < 576)
    r = pack4(*(const float4*)(src + elem0));
  ((unsigned long long*)dst)[li] = r;
}

// ---------------- 128x128 NT GEMM (m97 structure) for N%256 != 0 ----------------
template <int MODE>
__global__ __launch_bounds__(256) void gemm_nt(const u16* __restrict__ A, int lda,
                                               const u16* __restrict__ B, int ldb,
                                               void* __restrict__ Cv, int ldc,
                                               u16* __restrict__ Vc, int K) {
  __shared__ u16 As[128 * 64];
  __shared__ u16 Bs[128 * 64];
  const int tid = threadIdx.x;
  const int lane = tid & 63, wid = tid >> 6;
  const int l15 = lane & 15, l4 = lane >> 4;
  const int wr = wid >> 1, wc = wid & 1;
  const long bm = (long)blockIdx.y * 128;
  const long bn = (long)blockIdx.x * 128;

  const int srow = wid * 32 + (lane >> 3);
  const int scol = (lane & 7) * 8;
  const u16* Ag = A + (bm + srow) * (long)lda + scol;
  const u16* Bg = B + (bn + srow) * (long)ldb + scol;
  u16* AsW = &As[wid * 32 * 64];
  u16* BsW = &Bs[wid * 32 * 64];

  f32x4 acc[4][4] = {};

  for (int k0 = 0; k0 < K; k0 += 64) {
    __syncthreads();
#pragma unroll
    for (int ch = 0; ch < 4; ++ch) {
      __builtin_amdgcn_global_load_lds((const GLV*)(Ag + (long)ch * 8 * lda + k0),
                                       (LDSV*)(AsW + ch * 512), 16, 0, 0);
      __builtin_amdgcn_global_load_lds((const GLV*)(Bg + (long)ch * 8 * ldb + k0),
                                       (LDSV*)(BsW + ch * 512), 16, 0, 0);
    }
    __syncthreads();
#pragma unroll
    for (int kk = 0; kk < 2; ++kk) {
      bf16x8 af[4], bfr[4];
#pragma unroll
      for (int m = 0; m < 4; ++m)
        af[m] = *(const bf16x8*)(&As[(wr * 64 + m * 16 + l15) * 64 + (kk * 4 + l4) * 8]);
#pragma unroll
      for (int n = 0; n < 4; ++n)
        bfr[n] = *(const bf16x8*)(&Bs[(wc * 64 + n * 16 + l15) * 64 + (kk * 4 + l4) * 8]);
#pragma unroll
      for (int m = 0; m < 4; ++m)
#pragma unroll
        for (int n = 0; n < 4; ++n)
          acc[m][n] = __builtin_amdgcn_mfma_f32_16x16x32_bf16(af[m], bfr[n], acc[m][n], 0, 0, 0);
    }
  }
#pragma unroll
  for (int m = 0; m < 4; ++m)
#pragma unroll
    for (int n = 0; n < 4; ++n)
#pragma unroll
      for (int r = 0; r < 4; ++r) {
        long row = bm + wr * 64 + m * 16 + l4 * 4 + r;
        long col = bn + wc * 64 + n * 16 + l15;
        float v = acc[m][n][r];
        if constexpr (MODE == 0) {
          ((u16*)Cv)[row * ldc + col] = f2bf(v);
        } else if constexpr (MODE == 1) {
          ((float*)Cv)[row * ldc + col] = v;
        } else {
          int h = (int)(col >> 8), c = (int)(col & 255);
          if (c < 128)
            ((u16*)Cv)[(((row >> 11) * 16 + h) * 2048 + (row & 2047)) * 128 + c] = f2bf(v);
          else
            Vc[row * 2048 + h * 128 + (c - 128)] = f2bf(v);
        }
      }
}

// ---------------- 256x256 8-phase NT GEMM (T2+T3+T4+T5) ----------------
// BM=BN=256, BK=64, 512 thr / 8 waves (2M x 4N interleaved). LDS 128KB:
// S[0..64KB) = A[2 buf][2 half][128x64], [64..128KB) = B same. 4 phases/tile,
// quadrant (qm,qn) reads exactly A-half qm + B-half qn. Raw s_barrier + counted
// vmcnt(4) at tile boundary only. Chunk-XOR swizzle (involution, 16B granular):
// both staged-source and ds_read apply  lin ^ ((row&7)<<4).
#define MM_PHASE(QM, QN, BB)                                                     \
  __builtin_amdgcn_s_setprio(1);                                                 \
  {                                                                              \
    _Pragma("unroll") for (int mf = 0; mf < 4; ++mf) {                           \
      _Pragma("unroll") for (int nf = 0; nf < 2; ++nf) {                         \
        _Pragma("unroll") for (int kk = 0; kk < 2; ++kk) {                       \
          acc[(QM) * 4 + mf][(QN) * 2 + nf] =                                    \
              __builtin_amdgcn_mfma_f32_16x16x32_bf16(                           \
                  a[mf][kk], BB[nf][kk], acc[(QM) * 4 + mf][(QN) * 2 + nf],      \
                  0, 0, 0);                                                      \
        }                                                                        \
      }                                                                          \
    }                                                                            \
  }                                                                              \
  __builtin_amdgcn_s_setprio(0);

template <int MODE>
__global__ __launch_bounds__(512, 2) void gemm256(const u16* __restrict__ A, int lda,
                                                  const u16* __restrict__ B, int ldb,
                                                  void* __restrict__ Cv, int ldc,
                                                  u16* __restrict__ Vc, int K) {
  __shared__ u16 SMEM[65536];  // 128 KB
  const int tid = threadIdx.x;
  const int lane = tid & 63, wid = tid >> 6;
  const int l15 = lane & 15, l4 = lane >> 4;
  const int wm16 = (wid >> 2) * 16, wn16 = (wid & 3) * 16;

  // XCD-bijective block swizzle (grid %8 == 0 for all our shapes)
  const int gx = gridDim.x, nwg = gx * gridDim.y;
  int lin0 = blockIdx.y * gx + blockIdx.x;
  int cpx = nwg >> 3;
  int swzb = (lin0 & 7) * cpx + (lin0 >> 3);
  const long bm = (long)(swzb / gx) * 256;
  const long bn = (long)(swzb % gx) * 256;

  // staging source offsets (pre-swizzled so linear LDS dest = swizzled content)
  long aoff[2], boff[2];
#pragma unroll
  for (int j = 0; j < 2; ++j) {
    int lb = (j * 512 + tid) * 16;
    int swz = lb ^ (((lb >> 7) & 7) << 4);
    int sr = swz >> 7, sc = (swz & 127) >> 1;
    aoff[j] = (bm + sr) * (long)lda + sc;
    boff[j] = (bn + sr) * (long)ldb + sc;
  }

  auto STAGE = [&](int buf, int half, int isB, int tt) {
#pragma unroll
    for (int j = 0; j < 2; ++j) {
      const u16* src = isB ? (B + boff[j] + (long)half * 128 * ldb + tt * 64)
                           : (A + aoff[j] + (long)half * 128 * lda + tt * 64);
      __builtin_amdgcn_global_load_lds(
          (const GLV*)src,
          (LDSV*)((char*)SMEM + isB * 65536 + buf * 32768 + half * 16384 +
                  (j * 512 + tid) * 16),
          16, 0, 0);
    }
  };

  f32x4 acc[8][4] = {};
  bf16x8 a[4][2], b0[2][2], b1[2][2];

  auto LDA_ = [&](int buf, int qm) {
#pragma unroll
    for (int mf = 0; mf < 4; ++mf)
#pragma unroll
      for (int kk = 0; kk < 2; ++kk) {
        int r = mf * 32 + wm16 + l15;
        int lb = r * 128 + kk * 64 + l4 * 16;
        a[mf][kk] = *(const bf16x8*)((char*)SMEM + buf * 32768 + qm * 16384 +
                                     (lb ^ ((r & 7) << 4)));
      }
  };
  auto LDB_ = [&](int buf, int qn, bf16x8 (*bb)[2]) {
#pragma unroll
    for (int nf = 0; nf < 2; ++nf)
#pragma unroll
      for (int kk = 0; kk < 2; ++kk) {
        int r = nf * 64 + wn16 + l15;
        int lb = r * 128 + kk * 64 + l4 * 16;
        bb[nf][kk] = *(const bf16x8*)((char*)SMEM + 65536 + buf * 32768 +
                                      qn * 16384 + (lb ^ ((r & 7) << 4)));
      }
  };

  const int NT = K >> 6;  // >= 2 always here
  // prologue: tile0 complete + tile1's Ah0,Bh0 in flight
  STAGE(0, 0, 0, 0); STAGE(0, 0, 1, 0); STAGE(0, 1, 1, 0); STAGE(0, 1, 0, 0);
  STAGE(1, 0, 0, 1); STAGE(1, 0, 1, 1);
  asm volatile("s_waitcnt vmcnt(4)" ::: "memory");
  __builtin_amdgcn_s_barrier();

  for (int t = 0; t < NT; ++t) {
    const int cb = t & 1;
    // P0 (qm0,qn0)
    if (t + 1 < NT) STAGE(cb ^ 1, 1, 1, t + 1);   // Bh1(t+1)
    LDA_(cb, 0);
    LDB_(cb, 0, b0);
    __builtin_amdgcn_s_barrier();
    asm volatile("s_waitcnt lgkmcnt(0)" ::: "memory");
    __builtin_amdgcn_sched_barrier(0);
    MM_PHASE(0, 0, b0);
    __builtin_amdgcn_s_barrier();
    // P1 (qm0,qn1)
    if (t + 1 < NT) STAGE(cb ^ 1, 1, 0, t + 1);   // Ah1(t+1)
    LDB_(cb, 1, b1);
    __builtin_amdgcn_s_barrier();
    asm volatile("s_waitcnt lgkmcnt(0)" ::: "memory");
    __builtin_amdgcn_sched_barrier(0);
    MM_PHASE(0, 1, b1);
    __builtin_amdgcn_s_barrier();
    // P2 (qm1,qn0)
    if (t + 2 < NT) STAGE(cb, 0, 0, t + 2);        // Ah0(t+2)
    LDA_(cb, 1);
    __builtin_amdgcn_s_barrier();
    asm volatile("s_waitcnt lgkmcnt(0)" ::: "memory");
    __builtin_amdgcn_sched_barrier(0);
    MM_PHASE(1, 0, b0);
    __builtin_amdgcn_s_barrier();
    // P3 (qm1,qn1)
    if (t + 2 < NT) STAGE(cb, 0, 1, t + 2);        // Bh0(t+2)
    __builtin_amdgcn_s_barrier();
    MM_PHASE(1, 1, b1);
    if (t + 2 < NT) asm volatile("s_waitcnt vmcnt(4)" ::: "memory");
    else            asm volatile("s_waitcnt vmcnt(0)" ::: "memory");
    __builtin_amdgcn_s_barrier();
  }

#pragma unroll
  for (int mfg = 0; mfg < 8; ++mfg)
#pragma unroll
    for (int nfg = 0; nfg < 4; ++nfg)
#pragma unroll
      for (int r = 0; r < 4; ++r) {
        long row = bm + mfg * 32 + wm16 + l4 * 4 + r;
        long col = bn + nfg * 64 + wn16 + l15;
        float v = acc[mfg][nfg][r];
        if constexpr (MODE == 0) {
          ((u16*)Cv)[row * ldc + col] = f2bf(v);
        } else if constexpr (MODE == 1) {
          ((float*)Cv)[row * ldc + col] = v;
        } else {
          int h = (int)(col >> 8), c = (int)(col & 255);
          if (c < 128)
            ((u16*)Cv)[(((row >> 11) * 16 + h) * 2048 + (row & 2047)) * 128 + c] = f2bf(v);
          else
            Vc[row * 2048 + h * 128 + (c - 128)] = f2bf(v);
        }
      }
}

// ---------------- both RMSNorms in one dispatch ----------------
__global__ __launch_bounds__(256) void rmsnorm2_kernel(u16* __restrict__ qakv,
                                                       const float* __restrict__ qw,
                                                       const float* __restrict__ kvw) {
  __shared__ float sred[4];
  const int tid = threadIdx.x;
  const int row = blockIdx.x;
  if (row < 4096) {
    u16* p = qakv + (size_t)row * 1408;
    float x[3];
    float ss = 0.f;
#pragma unroll
    for (int i = 0; i < 3; ++i) { x[i] = bf2f(p[tid + i * 256]); ss += x[i] * x[i]; }
#pragma unroll
    for (int off = 1; off < 64; off <<= 1) ss += __shfl_xor(ss, off);
    if ((tid & 63) == 0) sred[tid >> 6] = ss;
    __syncthreads();
    float tot = sred[0] + sred[1] + sred[2] + sred[3];
    float rs = rsqrtf(tot * (1.0f / 768.0f) + 1e-6f) * 0.0069411711f;  // SCALE*log2e/15
#pragma unroll
    for (int i = 0; i < 3; ++i) p[tid + i * 256] = f2bf(x[i] * rs * qw[tid + i * 256]);
  } else {
    u16* p = qakv + (size_t)(row - 4096) * 1408 + 768;
    float x[2];
    float ss = 0.f;
#pragma unroll
    for (int i = 0; i < 2; ++i) { x[i] = bf2f(p[tid + i * 256]); ss += x[i] * x[i]; }
#pragma unroll
    for (int off = 1; off < 64; off <<= 1) ss += __shfl_xor(ss, off);
    if ((tid & 63) == 0) sred[tid >> 6] = ss;
    __syncthreads();
    float tot = sred[0] + sred[1] + sred[2] + sred[3];
    float rs = rsqrtf(tot * (1.0f / 512.0f) + 1e-6f);
#pragma unroll
    for (int i = 0; i < 2; ++i) p[tid + i * 256] = f2bf(x[i] * rs * kvw[tid + i * 256]);
  }
}

// ---------------- RoPE on q_pe (in-place on q [4096][3072]) ----------------
__global__ __launch_bounds__(256) void rope_q_kernel(u16* __restrict__ q,
                                                     const float* __restrict__ cosb,
                                                     const float* __restrict__ sinb,
                                                     const float* __restrict__ gain) {
  int idx = blockIdx.x * 256 + threadIdx.x;
  int i = idx & 31;
  int h = (idx >> 5) & 15;
  int srow = idx >> 9;
  int s = srow & (S_LEN - 1);
  size_t base = (size_t)srow * 3072 + h * 192 + 128 + 2 * i;
  unsigned int* p = (unsigned int*)(q + base);
  unsigned int v = *p;
  float xe = bf2f((u16)(v & 0xffff)), xo = bf2f((u16)(v >> 16));
  float c = cosb[s * 32 + i], sn = sinb[s * 32 + i];
  float g = gain[h];
  float ye = (xe * c - xo * sn) * g, yo = (xe * sn + xo * c) * g;
  *p = (unsigned int)f2bf(ye) | ((unsigned int)f2bf(yo) << 16);
}

// ---------------- RoPE on k_pe -> compact kpe [b*S][64] ----------------
__global__ __launch_bounds__(256) void ropek_kernel(const u16* __restrict__ qakv,
                                                    const float* __restrict__ cosb,
                                                    const float* __restrict__ sinb,
                                                    u16* __restrict__ kpe) {
  int idx = blockIdx.x * 256 + threadIdx.x;
  int i = idx & 31;
  int srow = idx >> 5;
  int s = srow & 2047;
  unsigned int v = *(const unsigned int*)(qakv + (size_t)srow * 1408 + 1280 + 2 * i);
  float xe = bf2f((u16)(v & 0xffff)), xo = bf2f((u16)(v >> 16));
  float c = cosb[s * 32 + i], sn = sinb[s * 32 + i];
  *(unsigned int*)(kpe + (size_t)srow * 64 + 2 * i) =
      (unsigned int)f2bf(xe * c - xo * sn) | ((unsigned int)f2bf(xe * sn + xo * c) << 16);
}

// ---------------- V transpose: VT [B*H][128][S] from Vc [B*S][2048] ----------------
__global__ __launch_bounds__(256) void v_transpose_kernel(const u16* __restrict__ Vc,
                                                          u16* __restrict__ VT) {
  __shared__ u16 tile[64][65];
  int bh = blockIdx.z;
  int d0 = blockIdx.y * 64;
  int t0 = blockIdx.x * 64;
  int b = bh >> 4, h = bh & 15;
#pragma unroll
  for (int i = 0; i < 2; ++i) {
    int flat = i * 256 + threadIdx.x;
    int t = flat >> 3, c = (flat & 7) * 8;
    u32x4 v = *(const u32x4*)(Vc + ((long)b * S_LEN + t0 + t) * 2048 + h * 128 + d0 + c);
    const u16* pv = (const u16*)&v;
#pragma unroll
    for (int j = 0; j < 8; ++j) tile[c + j][t] = pv[j];
  }
  __syncthreads();
#pragma unroll
  for (int i = 0; i < 2; ++i) {
    int flat = i * 256 + threadIdx.x;
    int d = flat >> 3, tc = (flat & 7) * 8;
    u32x4 v;
    u16* pv = (u16*)&v;
#pragma unroll
    for (int j = 0; j < 8; ++j) pv[j] = tile[d][tc + j];
    *(u32x4*)(VT + ((long)bh * 128 + d0 + d) * S_LEN + t0 + tc) = v;
  }
}

// ---------------- fused causal attention + softcap + v-projection removal ----------
__global__ __launch_bounds__(512, 2) void attn_kernel(const u16* __restrict__ Qg,
                                                      const u16* __restrict__ KbN,
                                                      const u16* __restrict__ Kpe,
                                                      const u16* __restrict__ VTg,
                                                      const u16* __restrict__ Vcg,
                                                      u16* __restrict__ Yg) {
  __shared__ u16 Ks[64 * 192];
  __shared__ u16 VTs[128 * 64];
  __shared__ u16 Ps[128 * 64];

  const int tid = threadIdx.x, lane = tid & 63, wid = tid >> 6;
  const int l15 = lane & 15, l4 = lane >> 4;

  const int p = blockIdx.x;
  const int bh = (p & 7) * 4 + (p >> 6);
  const int pair = (p >> 3) & 7;
  const int b = bh >> 4, h = bh & 15;

  const u16* Kn = KbN + (long)bh * S_LEN * 128;
  const u16* Kp = Kpe + (long)b * S_LEN * 64;
  const u16* Vbh = VTg + (long)bh * 128 * S_LEN;

  int krow[3], sst[3];
  const u16* sb[3];
  u16* ksw[3];
#pragma unroll
  for (int i = 0; i < 3; ++i) {
    int flat = i * 512 + tid;
    int r = flat / 24, c = flat % 24;
    krow[i] = r;
    if (c < 16) { sb[i] = Kn + c * 8; sst[i] = 128; }
    else        { sb[i] = Kp + (c - 16) * 8; sst[i] = 64; }
    ksw[i] = &Ks[r * 192 + ((c ^ (r & 7)) * 8)];
  }
  int vrow[2], vc[2];
  u16* vsw[2];
#pragma unroll
  for (int i = 0; i < 2; ++i) {
    int flat = i * 512 + tid;
    vrow[i] = flat >> 3; vc[i] = flat & 7;
    vsw[i] = &VTs[vrow[i] * 64 + ((vc[i] ^ (vrow[i] & 7)) * 8)];
  }

  const int prow = wid * 16 + l15;
  const int pr7 = prow & 7;

  for (int seg = 0; seg < 2; ++seg) {
    const int qt = seg ? pair : 15 - pair;
    const int q0 = qt * 128;
    const int nkt = 2 * qt + 2;

    bf16x8 qf[6];
    {
      const u16* qb_ = Qg + ((long)b * S_LEN + q0 + prow) * 3072 + h * 192;
#pragma unroll
      for (int f = 0; f < 6; ++f) qf[f] = *(const bf16x8*)(qb_ + f * 32 + 8 * l4);
    }

    f32x4 o[8] = {};
    float lsum = 0.f;

    u32x4 ka[3], va[2];
#pragma unroll
    for (int i = 0; i < 3; ++i)
      ka[i] = *(const u32x4*)(sb[i] + (long)krow[i] * sst[i]);
#pragma unroll
    for (int i = 0; i < 2; ++i)
      va[i] = *(const u32x4*)(Vbh + (long)vrow[i] * S_LEN + vc[i] * 8);

    for (int it = 0; it < nkt; ++it) {
      __syncthreads();
#pragma unroll
      for (int i = 0; i < 3; ++i) *(u32x4*)ksw[i] = ka[i];
#pragma unroll
      for (int i = 0; i < 2; ++i) *(u32x4*)vsw[i] = va[i];
      __syncthreads();
      if (it + 1 < nkt) {
        int k0n = (it + 1) * 64;
#pragma unroll
        for (int i = 0; i < 3; ++i)
          ka[i] = *(const u32x4*)(sb[i] + (long)(k0n + krow[i]) * sst[i]);
#pragma unroll
        for (int i = 0; i < 2; ++i)
          va[i] = *(const u32x4*)(Vbh + (long)vrow[i] * S_LEN + k0n + vc[i] * 8);
      }

      f32x4 sacc[4] = {};
      __builtin_amdgcn_s_setprio(1);
#pragma unroll
      for (int f = 0; f < 6; ++f)
#pragma unroll
        for (int tf = 0; tf < 4; ++tf) {
          int row = tf * 16 + l15;
          bf16x8 kf = *(const bf16x8*)(&Ks[row * 192 + (((f * 4 + l4) ^ (row & 7)) * 8)]);
          sacc[tf] = __builtin_amdgcn_mfma_f32_16x16x32_bf16(kf, qf[f], sacc[tf], 0, 0, 0);
        }
      __builtin_amdgcn_s_setprio(0);

#pragma unroll
      for (int tf = 0; tf < 4; ++tf)
#pragma unroll
        for (int r = 0; r < 4; ++r) {
          float u = __builtin_amdgcn_exp2f(sacc[tf][r]);
          sacc[tf][r] = __builtin_amdgcn_exp2f(-86.56170245333781f *
                                               __builtin_amdgcn_rcpf(u + 1.0f));
        }
      if (it * 64 >= q0) {
        const int dthr = q0 + prow - it * 64 - l4 * 4;
#pragma unroll
        for (int tf = 0; tf < 4; ++tf)
#pragma unroll
          for (int r = 0; r < 4; ++r)
            if (tf * 16 + r > dthr) sacc[tf][r] = 0.f;
      }
#pragma unroll
      for (int tf = 0; tf < 4; ++tf)
#pragma unroll
        for (int r = 0; r < 4; ++r) lsum += sacc[tf][r];

#pragma unroll
      for (int tf = 0; tf < 4; ++tf) {
        u32x2 w;
        w.x = cvtpk(sacc[tf][0], sacc[tf][1]);
        w.y = cvtpk(sacc[tf][2], sacc[tf][3]);
        int chunk = tf * 2 + (l4 >> 1);
        *(u32x2*)(&Ps[prow * 64 + ((chunk ^ pr7) * 8) + (l4 & 1) * 4]) = w;
      }

      __builtin_amdgcn_s_setprio(1);
#pragma unroll
      for (int kk = 0; kk < 2; ++kk) {
        bf16x8 pf = *(const bf16x8*)(&Ps[prow * 64 + (((kk * 4 + l4) ^ pr7) * 8)]);
#pragma unroll
        for (int nf = 0; nf < 8; ++nf) {
          int vr = nf * 16 + l15;
          bf16x8 vf = *(const bf16x8*)(&VTs[vr * 64 + (((kk * 4 + l4) ^ (vr & 7)) * 8)]);
          o[nf] = __builtin_amdgcn_mfma_f32_16x16x32_bf16(pf, vf, o[nf], 0, 0, 0);
        }
      }
      __builtin_amdgcn_s_setprio(0);
    }

    lsum += __shfl_xor(lsum, 16);
    lsum += __shfl_xor(lsum, 32);
    float inv[4];
#pragma unroll
    for (int r = 0; r < 4; ++r)
      inv[r] = __builtin_amdgcn_rcpf(__shfl(lsum, (wid << 6 & 0) + l4 * 4 + r));

    float yv[8][4], vvv[8][4];
    float ssum[4] = {0.f, 0.f, 0.f, 0.f}, dsum[4] = {0.f, 0.f, 0.f, 0.f};
    const u16* vb = Vcg + ((long)b * S_LEN + q0 + wid * 16) * 2048 + h * 128;
#pragma unroll
    for (int nf = 0; nf < 8; ++nf)
#pragma unroll
      for (int r = 0; r < 4; ++r) {
        float vv = bf2f(vb[(l4 * 4 + r) * 2048 + nf * 16 + l15]);
        float y = o[nf][r] * inv[r];
        vvv[nf][r] = vv; yv[nf][r] = y;
        ssum[r] += vv * vv; dsum[r] += y * vv;
      }
#pragma unroll
    for (int r = 0; r < 4; ++r) {
      ssum[r] += __shfl_xor(ssum[r], 1); ssum[r] += __shfl_xor(ssum[r], 2);
      ssum[r] += __shfl_xor(ssum[r], 4); ssum[r] += __shfl_xor(ssum[r], 8);
      dsum[r] += __shfl_xor(dsum[r], 1); dsum[r] += __shfl_xor(dsum[r], 2);
      dsum[r] += __shfl_xor(dsum[r], 4); dsum[r] += __shfl_xor(dsum[r], 8);
      dsum[r] *= __builtin_amdgcn_rcpf(fmaxf(ssum[r], 1e-12f));
    }
#pragma unroll
    for (int nf = 0; nf < 8; ++nf)
#pragma unroll
      for (int r = 0; r < 4; ++r) {
        long row = (long)b * S_LEN + q0 + wid * 16 + l4 * 4 + r;
        Yg[row * 2048 + h * 128 + nf * 16 + l15] = f2bf(yv[nf][r] - dsum[r] * vvv[nf][r]);
      }
  }
}

extern "C" void kernel_launch(void* const* d_in, const int* in_sizes, int n_in,
                              void* d_out, int out_size, void* d_ws, size_t ws_size,
                              hipStream_t stream) {
  const float* x       = (const float*)d_in[0];
  const float* wq_a    = (const float*)d_in[1];
  const float* q_norm  = (const float*)d_in[2];
  const float* wq_b    = (const float*)d_in[3];
  const float* q_gain  = (const float*)d_in[4];
  const float* wkv_a   = (const float*)d_in[5];
  const float* kv_norm = (const float*)d_in[6];
  const float* wkv_b   = (const float*)d_in[7];
  const float* wo      = (const float*)d_in[8];
  const float* fcos    = (const float*)d_in[9];
  const float* fsin    = (const float*)d_in[10];
  float* out = (float*)d_out;

  char* ws = (char*)d_ws;
  size_t off = 0;
  auto alloc = [&](size_t bytes) {
    char* pp = ws + off;
    off += (bytes + 255) & ~(size_t)255;
    return pp;
  };
  const long M = 4096;  // B*S
  u16* xb    = (u16*)alloc(M * 2048 * 2);
  u16* wcomb = (u16*)alloc(1408L * 2048 * 2);
  u16* wqbb  = (u16*)alloc(3072L * 768 * 2);
  u16* wkvbb = (u16*)alloc(4096L * 512 * 2);
  u16* wob   = (u16*)alloc(2048L * 2048 * 2);
  u16* qakv  = (u16*)alloc(M * 1408 * 2);
  u16* qb    = (u16*)alloc(M * 3072 * 2);
  u16* KbN   = (u16*)alloc(32L * 2048 * 128 * 2);
  u16* kpe   = (u16*)alloc(M * 64 * 2);
  u16* Vc    = (u16*)alloc(M * 2048 * 2);
  u16* VTb   = (u16*)alloc(32L * 128 * 2048 * 2);
  u16* Yb    = (u16*)alloc(M * 2048 * 2);

  const long n4_x = 2097152, n4_wqa = 393216, n4_wqb = 589824,
             n4_wkvb = 524288, n4_wo = 1048576, n4_wkvap = 327680;
  long e0 = n4_x, e1 = e0 + n4_wqa, e2 = e1 + n4_wqb, e3 = e2 + n4_wkvb,
       e4 = e3 + n4_wo, e5 = e4 + n4_wkvap;
  cast_all<<<(int)(e5 / 256), 256, 0, stream>>>(
      x, xb, e0, wq_a, wcomb, e1, wq_b, wqbb, e2, wkv_b, wkvbb, e3,
      wo, wob, e4, wkv_a, wcomb + 768L * 2048, e5);

  // fused: [q_a | kv_full] = x @ [wq_a; wkv_a]^T   (N=1408 -> keep 128^2 kernel)
  gemm_nt<0><<<dim3(11, 32), 256, 0, stream>>>(xb, 2048, wcomb, 2048, qakv, 1408, nullptr, 2048);
  rmsnorm2_kernel<<<8192, 256, 0, stream>>>(qakv, q_norm, kv_norm);
  // q = q_a @ wq_b^T  (8-phase 256^2)
  gemm256<0><<<dim3(12, 16), 512, 0, stream>>>(qakv, 1408, wqbb, 768, qb, 3072, nullptr, 768);
  rope_q_kernel<<<2097152 / 256, 256, 0, stream>>>(qb, fcos, fsin, q_gain);
  ropek_kernel<<<131072 / 256, 256, 0, stream>>>(qakv, fcos, fsin, kpe);
  // kvb = kv @ wkv_b^T, epilogue-split into KbN (k_nope) and Vc (v)  (8-phase)
  gemm256<2><<<dim3(16, 16), 512, 0, stream>>>(qakv + 768, 1408, wkvbb, 512, KbN, 0, Vc, 512);
  v_transpose_kernel<<<dim3(32, 2, 32), 256, 0, stream>>>(Vc, VTb);
  attn_kernel<<<256, 512, 0, stream>>>(qb, KbN, kpe, VTb, Vc, Yb);
  // out = y @ wo^T (f32 out)  (8-phase)
  gemm256<1><<<dim3(8, 16), 512, 0, stream>>>(Yb, 2048, wob, 2048, out, 2048, nullptr, 2048);
}

// Round 8
// 246.460 us; speedup vs baseline: 2.1534x; 1.1226x over previous
//
#include <hip/hip_runtime.h>
#include <stdint.h>

typedef unsigned short u16;
typedef __bf16 bf16x8 __attribute__((ext_vector_type(8)));
typedef float f32x4 __attribute__((ext_vector_type(4)));
typedef unsigned int u32x4 __attribute__((ext_vector_type(4)));
typedef unsigned int u32x2 __attribute__((ext_vector_type(2)));

typedef __attribute__((address_space(3))) void LDSV;
typedef __attribute__((address_space(1))) void GLV;

#define S_LEN 2048

__device__ __forceinline__ float bf2f(u16 u) {
  union { unsigned int i; float f; } v; v.i = ((unsigned int)u) << 16; return v.f;
}
__device__ __forceinline__ u16 f2bf(float f) {
  union { float f; unsigned int i; } v; v.f = f;
  unsigned int x = v.i;
  return (u16)((x + 0x7fffu + ((x >> 16) & 1u)) >> 16);
}
__device__ __forceinline__ unsigned int cvtpk(float lo, float hi) {
  unsigned int r;
  asm("v_cvt_pk_bf16_f32 %0, %1, %2" : "=v"(r) : "v"(lo), "v"(hi));
  return r;
}
__device__ __forceinline__ unsigned long long pack4(float4 v) {
  return (unsigned long long)f2bf(v.x)
       | ((unsigned long long)f2bf(v.y) << 16)
       | ((unsigned long long)f2bf(v.z) << 32)
       | ((unsigned long long)f2bf(v.w) << 48);
}

// ---------------- all casts in one dispatch ----------------
__global__ __launch_bounds__(256) void cast_all(
    const float* __restrict__ s0, u16* __restrict__ d0, long e0,
    const float* __restrict__ s1, u16* __restrict__ d1, long e1,
    const float* __restrict__ s2, u16* __restrict__ d2, long e2,
    const float* __restrict__ s3, u16* __restrict__ d3, long e3,
    const float* __restrict__ s4, u16* __restrict__ d4, long e4,
    const float* __restrict__ s5, u16* __restrict__ d5, long e5) {
  long i = (long)blockIdx.x * 256 + threadIdx.x;
  const float* src; u16* dst; long base; bool pad = false;
  if (i < e0)      { src = s0; dst = d0; base = 0; }
  else if (i < e1) { src = s1; dst = d1; base = e0; }
  else if (i < e2) { src = s2; dst = d2; base = e1; }
  else if (i < e3) { src = s3; dst = d3; base = e2; }
  else if (i < e4) { src = s4; dst = d4; base = e3; }
  else if (i < e5) { src = s5; dst = d5; base = e4; pad = true; }
  else return;
  long li = i - base;
  long elem0 = li * 4;
  unsigned long long r = 0;
  if (!pad || (elem0 >> 11) < 576)
    r = pack4(*(const float4*)(src + elem0));
  ((unsigned long long*)dst)[li] = r;
}

// ---------------- 128x128 NT GEMM (m97 structure) ----------------
template <int MODE>
__global__ __launch_bounds__(256) void gemm_nt(const u16* __restrict__ A, int lda,
                                               const u16* __restrict__ B, int ldb,
                                               void* __restrict__ Cv, int ldc,
                                               u16* __restrict__ Vc, int K) {
  __shared__ u16 As[128 * 64];
  __shared__ u16 Bs[128 * 64];
  const int tid = threadIdx.x;
  const int lane = tid & 63, wid = tid >> 6;
  const int l15 = lane & 15, l4 = lane >> 4;
  const int wr = wid >> 1, wc = wid & 1;
  const long bm = (long)blockIdx.y * 128;
  const long bn = (long)blockIdx.x * 128;

  const int srow = wid * 32 + (lane >> 3);
  const int scol = (lane & 7) * 8;
  const u16* Ag = A + (bm + srow) * (long)lda + scol;
  const u16* Bg = B + (bn + srow) * (long)ldb + scol;
  u16* AsW = &As[wid * 32 * 64];
  u16* BsW = &Bs[wid * 32 * 64];

  f32x4 acc[4][4] = {};

  for (int k0 = 0; k0 < K; k0 += 64) {
    __syncthreads();
#pragma unroll
    for (int ch = 0; ch < 4; ++ch) {
      __builtin_amdgcn_global_load_lds((const GLV*)(Ag + (long)ch * 8 * lda + k0),
                                       (LDSV*)(AsW + ch * 512), 16, 0, 0);
      __builtin_amdgcn_global_load_lds((const GLV*)(Bg + (long)ch * 8 * ldb + k0),
                                       (LDSV*)(BsW + ch * 512), 16, 0, 0);
    }
    __syncthreads();
#pragma unroll
    for (int kk = 0; kk < 2; ++kk) {
      bf16x8 af[4], bfr[4];
#pragma unroll
      for (int m = 0; m < 4; ++m)
        af[m] = *(const bf16x8*)(&As[(wr * 64 + m * 16 + l15) * 64 + (kk * 4 + l4) * 8]);
#pragma unroll
      for (int n = 0; n < 4; ++n)
        bfr[n] = *(const bf16x8*)(&Bs[(wc * 64 + n * 16 + l15) * 64 + (kk * 4 + l4) * 8]);
#pragma unroll
      for (int m = 0; m < 4; ++m)
#pragma unroll
        for (int n = 0; n < 4; ++n)
          acc[m][n] = __builtin_amdgcn_mfma_f32_16x16x32_bf16(af[m], bfr[n], acc[m][n], 0, 0, 0);
    }
  }
#pragma unroll
  for (int m = 0; m < 4; ++m)
#pragma unroll
    for (int n = 0; n < 4; ++n)
#pragma unroll
      for (int r = 0; r < 4; ++r) {
        long row = bm + wr * 64 + m * 16 + l4 * 4 + r;
        long col = bn + wc * 64 + n * 16 + l15;
        float v = acc[m][n][r];
        if constexpr (MODE == 0) {
          ((u16*)Cv)[row * ldc + col] = f2bf(v);
        } else if constexpr (MODE == 1) {
          ((float*)Cv)[row * ldc + col] = v;
        } else {
          int h = (int)(col >> 8), c = (int)(col & 255);
          if (c < 128)
            ((u16*)Cv)[(((row >> 11) * 16 + h) * 2048 + (row & 2047)) * 128 + c] = f2bf(v);
          else
            Vc[row * 2048 + h * 128 + (c - 128)] = f2bf(v);
        }
      }
}

// ---------------- 256x256 8-phase NT GEMM (T2+T3+T4+T5) ----------------
#define MM_PHASE(QM, QN, BB)                                                     \
  __builtin_amdgcn_s_setprio(1);                                                 \
  {                                                                              \
    _Pragma("unroll") for (int mf = 0; mf < 4; ++mf) {                           \
      _Pragma("unroll") for (int nf = 0; nf < 2; ++nf) {                         \
        _Pragma("unroll") for (int kk = 0; kk < 2; ++kk) {                       \
          acc[(QM) * 4 + mf][(QN) * 2 + nf] =                                    \
              __builtin_amdgcn_mfma_f32_16x16x32_bf16(                           \
                  a[mf][kk], BB[nf][kk], acc[(QM) * 4 + mf][(QN) * 2 + nf],      \
                  0, 0, 0);                                                      \
        }                                                                        \
      }                                                                          \
    }                                                                            \
  }                                                                              \
  __builtin_amdgcn_s_setprio(0);

template <int MODE>
__global__ __launch_bounds__(512, 2) void gemm256(const u16* __restrict__ A, int lda,
                                                  const u16* __restrict__ B, int ldb,
                                                  void* __restrict__ Cv, int ldc,
                                                  u16* __restrict__ Vc, int K) {
  __shared__ u16 SMEM[65536];  // 128 KB
  const int tid = threadIdx.x;
  const int lane = tid & 63, wid = tid >> 6;
  const int l15 = lane & 15, l4 = lane >> 4;
  const int wm16 = (wid >> 2) * 16, wn16 = (wid & 3) * 16;

  const int gx = gridDim.x, nwg = gx * gridDim.y;
  int lin0 = blockIdx.y * gx + blockIdx.x;
  int cpx = nwg >> 3;
  int swzb = (lin0 & 7) * cpx + (lin0 >> 3);
  const long bm = (long)(swzb / gx) * 256;
  const long bn = (long)(swzb % gx) * 256;

  long aoff[2], boff[2];
#pragma unroll
  for (int j = 0; j < 2; ++j) {
    int lb = (j * 512 + tid) * 16;
    int swz = lb ^ (((lb >> 7) & 7) << 4);
    int sr = swz >> 7, sc = (swz & 127) >> 1;
    aoff[j] = (bm + sr) * (long)lda + sc;
    boff[j] = (bn + sr) * (long)ldb + sc;
  }

  auto STAGE = [&](int buf, int half, int isB, int tt) {
#pragma unroll
    for (int j = 0; j < 2; ++j) {
      const u16* src = isB ? (B + boff[j] + (long)half * 128 * ldb + tt * 64)
                           : (A + aoff[j] + (long)half * 128 * lda + tt * 64);
      __builtin_amdgcn_global_load_lds(
          (const GLV*)src,
          (LDSV*)((char*)SMEM + isB * 65536 + buf * 32768 + half * 16384 +
                  (j * 512 + tid) * 16),
          16, 0, 0);
    }
  };

  f32x4 acc[8][4] = {};
  bf16x8 a[4][2], b0[2][2], b1[2][2];

  auto LDA_ = [&](int buf, int qm) {
#pragma unroll
    for (int mf = 0; mf < 4; ++mf)
#pragma unroll
      for (int kk = 0; kk < 2; ++kk) {
        int r = mf * 32 + wm16 + l15;
        int lb = r * 128 + kk * 64 + l4 * 16;
        a[mf][kk] = *(const bf16x8*)((char*)SMEM + buf * 32768 + qm * 16384 +
                                     (lb ^ ((r & 7) << 4)));
      }
  };
  auto LDB_ = [&](int buf, int qn, bf16x8 (*bb)[2]) {
#pragma unroll
    for (int nf = 0; nf < 2; ++nf)
#pragma unroll
      for (int kk = 0; kk < 2; ++kk) {
        int r = nf * 64 + wn16 + l15;
        int lb = r * 128 + kk * 64 + l4 * 16;
        bb[nf][kk] = *(const bf16x8*)((char*)SMEM + 65536 + buf * 32768 +
                                      qn * 16384 + (lb ^ ((r & 7) << 4)));
      }
  };

  const int NT = K >> 6;
  STAGE(0, 0, 0, 0); STAGE(0, 0, 1, 0); STAGE(0, 1, 1, 0); STAGE(0, 1, 0, 0);
  STAGE(1, 0, 0, 1); STAGE(1, 0, 1, 1);
  asm volatile("s_waitcnt vmcnt(4)" ::: "memory");
  __builtin_amdgcn_s_barrier();

  for (int t = 0; t < NT; ++t) {
    const int cb = t & 1;
    if (t + 1 < NT) STAGE(cb ^ 1, 1, 1, t + 1);
    LDA_(cb, 0);
    LDB_(cb, 0, b0);
    __builtin_amdgcn_s_barrier();
    asm volatile("s_waitcnt lgkmcnt(0)" ::: "memory");
    __builtin_amdgcn_sched_barrier(0);
    MM_PHASE(0, 0, b0);
    __builtin_amdgcn_s_barrier();
    if (t + 1 < NT) STAGE(cb ^ 1, 1, 0, t + 1);
    LDB_(cb, 1, b1);
    __builtin_amdgcn_s_barrier();
    asm volatile("s_waitcnt lgkmcnt(0)" ::: "memory");
    __builtin_amdgcn_sched_barrier(0);
    MM_PHASE(0, 1, b1);
    __builtin_amdgcn_s_barrier();
    if (t + 2 < NT) STAGE(cb, 0, 0, t + 2);
    LDA_(cb, 1);
    __builtin_amdgcn_s_barrier();
    asm volatile("s_waitcnt lgkmcnt(0)" ::: "memory");
    __builtin_amdgcn_sched_barrier(0);
    MM_PHASE(1, 0, b0);
    __builtin_amdgcn_s_barrier();
    if (t + 2 < NT) STAGE(cb, 0, 1, t + 2);
    __builtin_amdgcn_s_barrier();
    MM_PHASE(1, 1, b1);
    if (t + 2 < NT) asm volatile("s_waitcnt vmcnt(4)" ::: "memory");
    else            asm volatile("s_waitcnt vmcnt(0)" ::: "memory");
    __builtin_amdgcn_s_barrier();
  }

#pragma unroll
  for (int mfg = 0; mfg < 8; ++mfg)
#pragma unroll
    for (int nfg = 0; nfg < 4; ++nfg)
#pragma unroll
      for (int r = 0; r < 4; ++r) {
        long row = bm + mfg * 32 + wm16 + l4 * 4 + r;
        long col = bn + nfg * 64 + wn16 + l15;
        float v = acc[mfg][nfg][r];
        if constexpr (MODE == 0) {
          ((u16*)Cv)[row * ldc + col] = f2bf(v);
        } else if constexpr (MODE == 1) {
          ((float*)Cv)[row * ldc + col] = v;
        } else {
          int h = (int)(col >> 8), c = (int)(col & 255);
          if (c < 128)
            ((u16*)Cv)[(((row >> 11) * 16 + h) * 2048 + (row & 2047)) * 128 + c] = f2bf(v);
          else
            Vc[row * 2048 + h * 128 + (c - 128)] = f2bf(v);
        }
      }
}

// ---------------- 256x128 4-phase NT GEMM (tall variant, 96KB LDS) ----------------
// BM=256 (2 halves x 128), BN=128 (2 halves x 64), BK=64. 8 waves 2M x 4N:
// per-wave 128x32 output (4 mf x 1 nf per quadrant). Per-tile loads: A 2+2, B 1+1
// instrs -> steady-state vmcnt(6), prologue vmcnt(3).
#define MM_TALL(QM, QN, BB)                                                      \
  __builtin_amdgcn_s_setprio(1);                                                 \
  {                                                                              \
    _Pragma("unroll") for (int mf = 0; mf < 4; ++mf) {                           \
      _Pragma("unroll") for (int kk = 0; kk < 2; ++kk) {                         \
        acc[(QM) * 4 + mf][(QN)] = __builtin_amdgcn_mfma_f32_16x16x32_bf16(      \
            a[mf][kk], BB[kk], acc[(QM) * 4 + mf][(QN)], 0, 0, 0);               \
      }                                                                          \
    }                                                                            \
  }                                                                              \
  __builtin_amdgcn_s_setprio(0);

template <int MODE>
__global__ __launch_bounds__(512, 2) void gemm_tall(const u16* __restrict__ A, int lda,
                                                    const u16* __restrict__ B, int ldb,
                                                    void* __restrict__ Cv, int ldc,
                                                    u16* __restrict__ Vc, int K) {
  __shared__ u16 SMEM[49152];  // 96 KB: A 64KB | B 32KB
  const int tid = threadIdx.x;
  const int lane = tid & 63, wid = tid >> 6;
  const int l15 = lane & 15, l4 = lane >> 4;
  const int wm16 = (wid >> 2) * 16, wn16 = (wid & 3) * 16;

  const int gx = gridDim.x, nwg = gx * gridDim.y;
  int lin0 = blockIdx.y * gx + blockIdx.x;
  int cpx = nwg >> 3;
  int swzb = (lin0 & 7) * cpx + (lin0 >> 3);
  const long bm = (long)(swzb / gx) * 256;
  const long bn = (long)(swzb % gx) * 128;

  long aoff[2], boffv;
#pragma unroll
  for (int j = 0; j < 2; ++j) {
    int lb = (j * 512 + tid) * 16;
    int swz = lb ^ (((lb >> 7) & 7) << 4);
    aoff[j] = (bm + (swz >> 7)) * (long)lda + ((swz & 127) >> 1);
  }
  {
    int lb = tid * 16;
    int swz = lb ^ (((lb >> 7) & 7) << 4);
    boffv = (bn + (swz >> 7)) * (long)ldb + ((swz & 127) >> 1);
  }

  auto SA = [&](int buf, int half, int tt) {
#pragma unroll
    for (int j = 0; j < 2; ++j)
      __builtin_amdgcn_global_load_lds(
          (const GLV*)(A + aoff[j] + (long)half * 128 * lda + tt * 64),
          (LDSV*)((char*)SMEM + buf * 32768 + half * 16384 + (j * 512 + tid) * 16),
          16, 0, 0);
  };
  auto SB = [&](int buf, int half, int tt) {
    __builtin_amdgcn_global_load_lds(
        (const GLV*)(B + boffv + (long)half * 64 * ldb + tt * 64),
        (LDSV*)((char*)SMEM + 65536 + buf * 16384 + half * 8192 + tid * 16),
        16, 0, 0);
  };

  f32x4 acc[8][2] = {};
  bf16x8 a[4][2], b0[2], b1[2];

  auto LDA_ = [&](int buf, int qm) {
#pragma unroll
    for (int mf = 0; mf < 4; ++mf)
#pragma unroll
      for (int kk = 0; kk < 2; ++kk) {
        int r = mf * 32 + wm16 + l15;
        int lb = r * 128 + kk * 64 + l4 * 16;
        a[mf][kk] = *(const bf16x8*)((char*)SMEM + buf * 32768 + qm * 16384 +
                                     (lb ^ ((r & 7) << 4)));
      }
  };
  auto LDB_ = [&](int buf, int qn, bf16x8* bb) {
#pragma unroll
    for (int kk = 0; kk < 2; ++kk) {
      int r = wn16 + l15;
      int lb = r * 128 + kk * 64 + l4 * 16;
      bb[kk] = *(const bf16x8*)((char*)SMEM + 65536 + buf * 16384 + qn * 8192 +
                                (lb ^ ((r & 7) << 4)));
    }
  };

  const int NT = K >> 6;
  SA(0, 0, 0); SB(0, 0, 0); SB(0, 1, 0); SA(0, 1, 0);
  SA(1, 0, 1); SB(1, 0, 1);
  asm volatile("s_waitcnt vmcnt(3)" ::: "memory");
  __builtin_amdgcn_s_barrier();

  for (int t = 0; t < NT; ++t) {
    const int cb = t & 1;
    if (t + 1 < NT) SB(cb ^ 1, 1, t + 1);
    LDA_(cb, 0);
    LDB_(cb, 0, b0);
    __builtin_amdgcn_s_barrier();
    asm volatile("s_waitcnt lgkmcnt(0)" ::: "memory");
    __builtin_amdgcn_sched_barrier(0);
    MM_TALL(0, 0, b0);
    __builtin_amdgcn_s_barrier();
    if (t + 1 < NT) SA(cb ^ 1, 1, t + 1);
    LDB_(cb, 1, b1);
    __builtin_amdgcn_s_barrier();
    asm volatile("s_waitcnt lgkmcnt(0)" ::: "memory");
    __builtin_amdgcn_sched_barrier(0);
    MM_TALL(0, 1, b1);
    __builtin_amdgcn_s_barrier();
    if (t + 2 < NT) SA(cb, 0, t + 2);
    LDA_(cb, 1);
    __builtin_amdgcn_s_barrier();
    asm volatile("s_waitcnt lgkmcnt(0)" ::: "memory");
    __builtin_amdgcn_sched_barrier(0);
    MM_TALL(1, 0, b0);
    __builtin_amdgcn_s_barrier();
    if (t + 2 < NT) SB(cb, 0, t + 2);
    __builtin_amdgcn_s_barrier();
    MM_TALL(1, 1, b1);
    if (t + 2 < NT) asm volatile("s_waitcnt vmcnt(6)" ::: "memory");
    else            asm volatile("s_waitcnt vmcnt(0)" ::: "memory");
    __builtin_amdgcn_s_barrier();
  }

#pragma unroll
  for (int mfg = 0; mfg < 8; ++mfg)
#pragma unroll
    for (int qn = 0; qn < 2; ++qn)
#pragma unroll
      for (int r = 0; r < 4; ++r) {
        long row = bm + mfg * 32 + wm16 + l4 * 4 + r;
        long col = bn + qn * 64 + wn16 + l15;
        float v = acc[mfg][qn][r];
        if constexpr (MODE == 0) {
          ((u16*)Cv)[row * ldc + col] = f2bf(v);
        } else if constexpr (MODE == 1) {
          ((float*)Cv)[row * ldc + col] = v;
        } else {
          int h = (int)(col >> 8), c = (int)(col & 255);
          if (c < 128)
            ((u16*)Cv)[(((row >> 11) * 16 + h) * 2048 + (row & 2047)) * 128 + c] = f2bf(v);
          else
            Vc[row * 2048 + h * 128 + (c - 128)] = f2bf(v);
        }
      }
}

// ---------------- both RMSNorms in one dispatch ----------------
__global__ __launch_bounds__(256) void rmsnorm2_kernel(u16* __restrict__ qakv,
                                                       const float* __restrict__ qw,
                                                       const float* __restrict__ kvw) {
  __shared__ float sred[4];
  const int tid = threadIdx.x;
  const int row = blockIdx.x;
  if (row < 4096) {
    u16* p = qakv + (size_t)row * 1408;
    float x[3];
    float ss = 0.f;
#pragma unroll
    for (int i = 0; i < 3; ++i) { x[i] = bf2f(p[tid + i * 256]); ss += x[i] * x[i]; }
#pragma unroll
    for (int off = 1; off < 64; off <<= 1) ss += __shfl_xor(ss, off);
    if ((tid & 63) == 0) sred[tid >> 6] = ss;
    __syncthreads();
    float tot = sred[0] + sred[1] + sred[2] + sred[3];
    float rs = rsqrtf(tot * (1.0f / 768.0f) + 1e-6f) * 0.0069411711f;  // SCALE*log2e/15
#pragma unroll
    for (int i = 0; i < 3; ++i) p[tid + i * 256] = f2bf(x[i] * rs * qw[tid + i * 256]);
  } else {
    u16* p = qakv + (size_t)(row - 4096) * 1408 + 768;
    float x[2];
    float ss = 0.f;
#pragma unroll
    for (int i = 0; i < 2; ++i) { x[i] = bf2f(p[tid + i * 256]); ss += x[i] * x[i]; }
#pragma unroll
    for (int off = 1; off < 64; off <<= 1) ss += __shfl_xor(ss, off);
    if ((tid & 63) == 0) sred[tid >> 6] = ss;
    __syncthreads();
    float tot = sred[0] + sred[1] + sred[2] + sred[3];
    float rs = rsqrtf(tot * (1.0f / 512.0f) + 1e-6f);
#pragma unroll
    for (int i = 0; i < 2; ++i) p[tid + i * 256] = f2bf(x[i] * rs * kvw[tid + i * 256]);
  }
}

// ---------------- RoPE on q_pe (in-place on q [4096][3072]) ----------------
__global__ __launch_bounds__(256) void rope_q_kernel(u16* __restrict__ q,
                                                     const float* __restrict__ cosb,
                                                     const float* __restrict__ sinb,
                                                     const float* __restrict__ gain) {
  int idx = blockIdx.x * 256 + threadIdx.x;
  int i = idx & 31;
  int h = (idx >> 5) & 15;
  int srow = idx >> 9;
  int s = srow & (S_LEN - 1);
  size_t base = (size_t)srow * 3072 + h * 192 + 128 + 2 * i;
  unsigned int* p = (unsigned int*)(q + base);
  unsigned int v = *p;
  float xe = bf2f((u16)(v & 0xffff)), xo = bf2f((u16)(v >> 16));
  float c = cosb[s * 32 + i], sn = sinb[s * 32 + i];
  float g = gain[h];
  float ye = (xe * c - xo * sn) * g, yo = (xe * sn + xo * c) * g;
  *p = (unsigned int)f2bf(ye) | ((unsigned int)f2bf(yo) << 16);
}

// ---------------- RoPE on k_pe -> compact kpe [b*S][64] ----------------
__global__ __launch_bounds__(256) void ropek_kernel(const u16* __restrict__ qakv,
                                                    const float* __restrict__ cosb,
                                                    const float* __restrict__ sinb,
                                                    u16* __restrict__ kpe) {
  int idx = blockIdx.x * 256 + threadIdx.x;
  int i = idx & 31;
  int srow = idx >> 5;
  int s = srow & 2047;
  unsigned int v = *(const unsigned int*)(qakv + (size_t)srow * 1408 + 1280 + 2 * i);
  float xe = bf2f((u16)(v & 0xffff)), xo = bf2f((u16)(v >> 16));
  float c = cosb[s * 32 + i], sn = sinb[s * 32 + i];
  *(unsigned int*)(kpe + (size_t)srow * 64 + 2 * i) =
      (unsigned int)f2bf(xe * c - xo * sn) | ((unsigned int)f2bf(xe * sn + xo * c) << 16);
}

// ---------------- V transpose: VT [B*H][128][S] from Vc [B*S][2048] ----------------
__global__ __launch_bounds__(256) void v_transpose_kernel(const u16* __restrict__ Vc,
                                                          u16* __restrict__ VT) {
  __shared__ u16 tile[64][65];
  int bh = blockIdx.z;
  int d0 = blockIdx.y * 64;
  int t0 = blockIdx.x * 64;
  int b = bh >> 4, h = bh & 15;
#pragma unroll
  for (int i = 0; i < 2; ++i) {
    int flat = i * 256 + threadIdx.x;
    int t = flat >> 3, c = (flat & 7) * 8;
    u32x4 v = *(const u32x4*)(Vc + ((long)b * S_LEN + t0 + t) * 2048 + h * 128 + d0 + c);
    const u16* pv = (const u16*)&v;
#pragma unroll
    for (int j = 0; j < 8; ++j) tile[c + j][t] = pv[j];
  }
  __syncthreads();
#pragma unroll
  for (int i = 0; i < 2; ++i) {
    int flat = i * 256 + threadIdx.x;
    int d = flat >> 3, tc = (flat & 7) * 8;
    u32x4 v;
    u16* pv = (u16*)&v;
#pragma unroll
    for (int j = 0; j < 8; ++j) pv[j] = tile[d][tc + j];
    *(u32x4*)(VT + ((long)bh * 128 + d0 + d) * S_LEN + t0 + tc) = v;
  }
}

// ---------------- fused causal attention + softcap + v-projection removal ----------
__global__ __launch_bounds__(512, 2) void attn_kernel(const u16* __restrict__ Qg,
                                                      const u16* __restrict__ KbN,
                                                      const u16* __restrict__ Kpe,
                                                      const u16* __restrict__ VTg,
                                                      const u16* __restrict__ Vcg,
                                                      u16* __restrict__ Yg) {
  __shared__ u16 Ks[64 * 192];
  __shared__ u16 VTs[128 * 64];
  __shared__ u16 Ps[128 * 64];

  const int tid = threadIdx.x, lane = tid & 63, wid = tid >> 6;
  const int l15 = lane & 15, l4 = lane >> 4;

  const int p = blockIdx.x;
  const int bh = (p & 7) * 4 + (p >> 6);
  const int pair = (p >> 3) & 7;
  const int b = bh >> 4, h = bh & 15;

  const u16* Kn = KbN + (long)bh * S_LEN * 128;
  const u16* Kp = Kpe + (long)b * S_LEN * 64;
  const u16* Vbh = VTg + (long)bh * 128 * S_LEN;

  int krow[3], sst[3];
  const u16* sb[3];
  u16* ksw[3];
#pragma unroll
  for (int i = 0; i < 3; ++i) {
    int flat = i * 512 + tid;
    int r = flat / 24, c = flat % 24;
    krow[i] = r;
    if (c < 16) { sb[i] = Kn + c * 8; sst[i] = 128; }
    else        { sb[i] = Kp + (c - 16) * 8; sst[i] = 64; }
    ksw[i] = &Ks[r * 192 + ((c ^ (r & 7)) * 8)];
  }
  int vrow[2], vc[2];
  u16* vsw[2];
#pragma unroll
  for (int i = 0; i < 2; ++i) {
    int flat = i * 512 + tid;
    vrow[i] = flat >> 3; vc[i] = flat & 7;
    vsw[i] = &VTs[vrow[i] * 64 + ((vc[i] ^ (vrow[i] & 7)) * 8)];
  }

  const int prow = wid * 16 + l15;
  const int pr7 = prow & 7;

  for (int seg = 0; seg < 2; ++seg) {
    const int qt = seg ? pair : 15 - pair;
    const int q0 = qt * 128;
    const int nkt = 2 * qt + 2;

    bf16x8 qf[6];
    {
      const u16* qb_ = Qg + ((long)b * S_LEN + q0 + prow) * 3072 + h * 192;
#pragma unroll
      for (int f = 0; f < 6; ++f) qf[f] = *(const bf16x8*)(qb_ + f * 32 + 8 * l4);
    }

    f32x4 o[8] = {};
    float lsum = 0.f;

    u32x4 ka[3], va[2];
#pragma unroll
    for (int i = 0; i < 3; ++i)
      ka[i] = *(const u32x4*)(sb[i] + (long)krow[i] * sst[i]);
#pragma unroll
    for (int i = 0; i < 2; ++i)
      va[i] = *(const u32x4*)(Vbh + (long)vrow[i] * S_LEN + vc[i] * 8);

    for (int it = 0; it < nkt; ++it) {
      __syncthreads();
#pragma unroll
      for (int i = 0; i < 3; ++i) *(u32x4*)ksw[i] = ka[i];
#pragma unroll
      for (int i = 0; i < 2; ++i) *(u32x4*)vsw[i] = va[i];
      __syncthreads();
      if (it + 1 < nkt) {
        int k0n = (it + 1) * 64;
#pragma unroll
        for (int i = 0; i < 3; ++i)
          ka[i] = *(const u32x4*)(sb[i] + (long)(k0n + krow[i]) * sst[i]);
#pragma unroll
        for (int i = 0; i < 2; ++i)
          va[i] = *(const u32x4*)(Vbh + (long)vrow[i] * S_LEN + k0n + vc[i] * 8);
      }

      f32x4 sacc[4] = {};
      __builtin_amdgcn_s_setprio(1);
#pragma unroll
      for (int f = 0; f < 6; ++f)
#pragma unroll
        for (int tf = 0; tf < 4; ++tf) {
          int row = tf * 16 + l15;
          bf16x8 kf = *(const bf16x8*)(&Ks[row * 192 + (((f * 4 + l4) ^ (row & 7)) * 8)]);
          sacc[tf] = __builtin_amdgcn_mfma_f32_16x16x32_bf16(kf, qf[f], sacc[tf], 0, 0, 0);
        }
      __builtin_amdgcn_s_setprio(0);

#pragma unroll
      for (int tf = 0; tf < 4; ++tf)
#pragma unroll
        for (int r = 0; r < 4; ++r) {
          float u = __builtin_amdgcn_exp2f(sacc[tf][r]);
          sacc[tf][r] = __builtin_amdgcn_exp2f(-86.56170245333781f *
                                               __builtin_amdgcn_rcpf(u + 1.0f));
        }
      if (it * 64 >= q0) {
        const int dthr = q0 + prow - it * 64 - l4 * 4;
#pragma unroll
        for (int tf = 0; tf < 4; ++tf)
#pragma unroll
          for (int r = 0; r < 4; ++r)
            if (tf * 16 + r > dthr) sacc[tf][r] = 0.f;
      }
#pragma unroll
      for (int tf = 0; tf < 4; ++tf)
#pragma unroll
        for (int r = 0; r < 4; ++r) lsum += sacc[tf][r];

#pragma unroll
      for (int tf = 0; tf < 4; ++tf) {
        u32x2 w;
        w.x = cvtpk(sacc[tf][0], sacc[tf][1]);
        w.y = cvtpk(sacc[tf][2], sacc[tf][3]);
        int chunk = tf * 2 + (l4 >> 1);
        *(u32x2*)(&Ps[prow * 64 + ((chunk ^ pr7) * 8) + (l4 & 1) * 4]) = w;
      }

      __builtin_amdgcn_s_setprio(1);
#pragma unroll
      for (int kk = 0; kk < 2; ++kk) {
        bf16x8 pf = *(const bf16x8*)(&Ps[prow * 64 + (((kk * 4 + l4) ^ pr7) * 8)]);
#pragma unroll
        for (int nf = 0; nf < 8; ++nf) {
          int vr = nf * 16 + l15;
          bf16x8 vf = *(const bf16x8*)(&VTs[vr * 64 + (((kk * 4 + l4) ^ (vr & 7)) * 8)]);
          o[nf] = __builtin_amdgcn_mfma_f32_16x16x32_bf16(pf, vf, o[nf], 0, 0, 0);
        }
      }
      __builtin_amdgcn_s_setprio(0);
    }

    lsum += __shfl_xor(lsum, 16);
    lsum += __shfl_xor(lsum, 32);
    float inv[4];
#pragma unroll
    for (int r = 0; r < 4; ++r)
      inv[r] = __builtin_amdgcn_rcpf(__shfl(lsum, l4 * 4 + r));

    float yv[8][4], vvv[8][4];
    float ssum[4] = {0.f, 0.f, 0.f, 0.f}, dsum[4] = {0.f, 0.f, 0.f, 0.f};
    const u16* vb = Vcg + ((long)b * S_LEN + q0 + wid * 16) * 2048 + h * 128;
#pragma unroll
    for (int nf = 0; nf < 8; ++nf)
#pragma unroll
      for (int r = 0; r < 4; ++r) {
        float vv = bf2f(vb[(l4 * 4 + r) * 2048 + nf * 16 + l15]);
        float y = o[nf][r] * inv[r];
        vvv[nf][r] = vv; yv[nf][r] = y;
        ssum[r] += vv * vv; dsum[r] += y * vv;
      }
#pragma unroll
    for (int r = 0; r < 4; ++r) {
      ssum[r] += __shfl_xor(ssum[r], 1); ssum[r] += __shfl_xor(ssum[r], 2);
      ssum[r] += __shfl_xor(ssum[r], 4); ssum[r] += __shfl_xor(ssum[r], 8);
      dsum[r] += __shfl_xor(dsum[r], 1); dsum[r] += __shfl_xor(dsum[r], 2);
      dsum[r] += __shfl_xor(dsum[r], 4); dsum[r] += __shfl_xor(dsum[r], 8);
      dsum[r] *= __builtin_amdgcn_rcpf(fmaxf(ssum[r], 1e-12f));
    }
#pragma unroll
    for (int nf = 0; nf < 8; ++nf)
#pragma unroll
      for (int r = 0; r < 4; ++r) {
        long row = (long)b * S_LEN + q0 + wid * 16 + l4 * 4 + r;
        Yg[row * 2048 + h * 128 + nf * 16 + l15] = f2bf(yv[nf][r] - dsum[r] * vvv[nf][r]);
      }
  }
}

extern "C" void kernel_launch(void* const* d_in, const int* in_sizes, int n_in,
                              void* d_out, int out_size, void* d_ws, size_t ws_size,
                              hipStream_t stream) {
  const float* x       = (const float*)d_in[0];
  const float* wq_a    = (const float*)d_in[1];
  const float* q_norm  = (const float*)d_in[2];
  const float* wq_b    = (const float*)d_in[3];
  const float* q_gain  = (const float*)d_in[4];
  const float* wkv_a   = (const float*)d_in[5];
  const float* kv_norm = (const float*)d_in[6];
  const float* wkv_b   = (const float*)d_in[7];
  const float* wo      = (const float*)d_in[8];
  const float* fcos    = (const float*)d_in[9];
  const float* fsin    = (const float*)d_in[10];
  float* out = (float*)d_out;

  char* ws = (char*)d_ws;
  size_t off = 0;
  auto alloc = [&](size_t bytes) {
    char* pp = ws + off;
    off += (bytes + 255) & ~(size_t)255;
    return pp;
  };
  const long M = 4096;  // B*S
  u16* xb    = (u16*)alloc(M * 2048 * 2);
  u16* wcomb = (u16*)alloc(1408L * 2048 * 2);
  u16* wqbb  = (u16*)alloc(3072L * 768 * 2);
  u16* wkvbb = (u16*)alloc(4096L * 512 * 2);
  u16* wob   = (u16*)alloc(2048L * 2048 * 2);
  u16* qakv  = (u16*)alloc(M * 1408 * 2);
  u16* qb    = (u16*)alloc(M * 3072 * 2);
  u16* KbN   = (u16*)alloc(32L * 2048 * 128 * 2);
  u16* kpe   = (u16*)alloc(M * 64 * 2);
  u16* Vc    = (u16*)alloc(M * 2048 * 2);
  u16* VTb   = (u16*)alloc(32L * 128 * 2048 * 2);
  u16* Yb    = (u16*)alloc(M * 2048 * 2);

  const long n4_x = 2097152, n4_wqa = 393216, n4_wqb = 589824,
             n4_wkvb = 524288, n4_wo = 1048576, n4_wkvap = 327680;
  long e0 = n4_x, e1 = e0 + n4_wqa, e2 = e1 + n4_wqb, e3 = e2 + n4_wkvb,
       e4 = e3 + n4_wo, e5 = e4 + n4_wkvap;
  cast_all<<<(int)(e5 / 256), 256, 0, stream>>>(
      x, xb, e0, wq_a, wcomb, e1, wq_b, wqbb, e2, wkv_b, wkvbb, e3,
      wo, wob, e4, wkv_a, wcomb + 768L * 2048, e5);

  // fused: [q_a | kv_full] = x @ [wq_a; wkv_a]^T   (N=1408, 256x128 tall, 176 blk)
  gemm_tall<0><<<dim3(11, 16), 512, 0, stream>>>(xb, 2048, wcomb, 2048, qakv, 1408, nullptr, 2048);
  rmsnorm2_kernel<<<8192, 256, 0, stream>>>(qakv, q_norm, kv_norm);
  // q = q_a @ wq_b^T  (8-phase 256^2, 192 blk)
  gemm256<0><<<dim3(12, 16), 512, 0, stream>>>(qakv, 1408, wqbb, 768, qb, 3072, nullptr, 768);
  rope_q_kernel<<<2097152 / 256, 256, 0, stream>>>(qb, fcos, fsin, q_gain);
  ropek_kernel<<<131072 / 256, 256, 0, stream>>>(qakv, fcos, fsin, kpe);
  // kvb = kv @ wkv_b^T, split epilogue  (8-phase 256^2, 256 blk)
  gemm256<2><<<dim3(16, 16), 512, 0, stream>>>(qakv + 768, 1408, wkvbb, 512, KbN, 0, Vc, 512);
  v_transpose_kernel<<<dim3(32, 2, 32), 256, 0, stream>>>(Vc, VTb);
  attn_kernel<<<256, 512, 0, stream>>>(qb, KbN, kpe, VTb, Vc, Yb);
  // out = y @ wo^T (f32 out)  (256x128 tall, 256 blk)
  gemm_tall<1><<<dim3(16, 16), 512, 0, stream>>>(Yb, 2048, wob, 2048, out, 2048, nullptr, 2048);
}

// Round 9
// 238.439 us; speedup vs baseline: 2.2258x; 1.0336x over previous
//
#include <hip/hip_runtime.h>
#include <stdint.h>

typedef unsigned short u16;
typedef __bf16 bf16x8 __attribute__((ext_vector_type(8)));
typedef float f32x4 __attribute__((ext_vector_type(4)));
typedef unsigned int u32x4 __attribute__((ext_vector_type(4)));
typedef unsigned int u32x2 __attribute__((ext_vector_type(2)));

typedef __attribute__((address_space(3))) void LDSV;
typedef __attribute__((address_space(1))) void GLV;

#define S_LEN 2048

__device__ __forceinline__ float bf2f(u16 u) {
  union { unsigned int i; float f; } v; v.i = ((unsigned int)u) << 16; return v.f;
}
__device__ __forceinline__ u16 f2bf(float f) {
  union { float f; unsigned int i; } v; v.f = f;
  unsigned int x = v.i;
  return (u16)((x + 0x7fffu + ((x >> 16) & 1u)) >> 16);
}
__device__ __forceinline__ unsigned int cvtpk(float lo, float hi) {
  unsigned int r;
  asm("v_cvt_pk_bf16_f32 %0, %1, %2" : "=v"(r) : "v"(lo), "v"(hi));
  return r;
}
__device__ __forceinline__ unsigned long long pack4(float4 v) {
  return (unsigned long long)f2bf(v.x)
       | ((unsigned long long)f2bf(v.y) << 16)
       | ((unsigned long long)f2bf(v.z) << 32)
       | ((unsigned long long)f2bf(v.w) << 48);
}

// ---------------- all casts in one dispatch ----------------
__global__ __launch_bounds__(256) void cast_all(
    const float* __restrict__ s0, u16* __restrict__ d0, long e0,
    const float* __restrict__ s1, u16* __restrict__ d1, long e1,
    const float* __restrict__ s2, u16* __restrict__ d2, long e2,
    const float* __restrict__ s3, u16* __restrict__ d3, long e3,
    const float* __restrict__ s4, u16* __restrict__ d4, long e4,
    const float* __restrict__ s5, u16* __restrict__ d5, long e5) {
  long i = (long)blockIdx.x * 256 + threadIdx.x;
  const float* src; u16* dst; long base; bool pad = false;
  if (i < e0)      { src = s0; dst = d0; base = 0; }
  else if (i < e1) { src = s1; dst = d1; base = e0; }
  else if (i < e2) { src = s2; dst = d2; base = e1; }
  else if (i < e3) { src = s3; dst = d3; base = e2; }
  else if (i < e4) { src = s4; dst = d4; base = e3; }
  else if (i < e5) { src = s5; dst = d5; base = e4; pad = true; }
  else return;
  long li = i - base;
  long elem0 = li * 4;
  unsigned long long r = 0;
  if (!pad || (elem0 >> 11) < 576)
    r = pack4(*(const float4*)(src + elem0));
  ((unsigned long long*)dst)[li] = r;
}

// ---------------- 256x256 8-phase NT GEMM (T2+T3+T4+T5) ----------------
#define MM_PHASE(QM, QN, BB)                                                     \
  __builtin_amdgcn_s_setprio(1);                                                 \
  {                                                                              \
    _Pragma("unroll") for (int mf = 0; mf < 4; ++mf) {                           \
      _Pragma("unroll") for (int nf = 0; nf < 2; ++nf) {                         \
        _Pragma("unroll") for (int kk = 0; kk < 2; ++kk) {                       \
          acc[(QM) * 4 + mf][(QN) * 2 + nf] =                                    \
              __builtin_amdgcn_mfma_f32_16x16x32_bf16(                           \
                  a[mf][kk], BB[nf][kk], acc[(QM) * 4 + mf][(QN) * 2 + nf],      \
                  0, 0, 0);                                                      \
        }                                                                        \
      }                                                                          \
    }                                                                            \
  }                                                                              \
  __builtin_amdgcn_s_setprio(0);

template <int MODE>
__global__ __launch_bounds__(512, 2) void gemm256(const u16* __restrict__ A, int lda,
                                                  const u16* __restrict__ B, int ldb,
                                                  void* __restrict__ Cv, int ldc,
                                                  u16* __restrict__ Vc, int K) {
  __shared__ u16 SMEM[65536];  // 128 KB
  const int tid = threadIdx.x;
  const int lane = tid & 63, wid = tid >> 6;
  const int l15 = lane & 15, l4 = lane >> 4;
  const int wm16 = (wid >> 2) * 16, wn16 = (wid & 3) * 16;

  const int gx = gridDim.x, nwg = gx * gridDim.y;
  int lin0 = blockIdx.y * gx + blockIdx.x;
  int cpx = nwg >> 3;
  int swzb = (lin0 & 7) * cpx + (lin0 >> 3);
  const long bm = (long)(swzb / gx) * 256;
  const long bn = (long)(swzb % gx) * 256;

  long aoff[2], boff[2];
#pragma unroll
  for (int j = 0; j < 2; ++j) {
    int lb = (j * 512 + tid) * 16;
    int swz = lb ^ (((lb >> 7) & 7) << 4);
    int sr = swz >> 7, sc = (swz & 127) >> 1;
    aoff[j] = (bm + sr) * (long)lda + sc;
    boff[j] = (bn + sr) * (long)ldb + sc;
  }

  auto STAGE = [&](int buf, int half, int isB, int tt) {
#pragma unroll
    for (int j = 0; j < 2; ++j) {
      const u16* src = isB ? (B + boff[j] + (long)half * 128 * ldb + tt * 64)
                           : (A + aoff[j] + (long)half * 128 * lda + tt * 64);
      __builtin_amdgcn_global_load_lds(
          (const GLV*)src,
          (LDSV*)((char*)SMEM + isB * 65536 + buf * 32768 + half * 16384 +
                  (j * 512 + tid) * 16),
          16, 0, 0);
    }
  };

  f32x4 acc[8][4] = {};
  bf16x8 a[4][2], b0[2][2], b1[2][2];

  auto LDA_ = [&](int buf, int qm) {
#pragma unroll
    for (int mf = 0; mf < 4; ++mf)
#pragma unroll
      for (int kk = 0; kk < 2; ++kk) {
        int r = mf * 32 + wm16 + l15;
        int lb = r * 128 + kk * 64 + l4 * 16;
        a[mf][kk] = *(const bf16x8*)((char*)SMEM + buf * 32768 + qm * 16384 +
                                     (lb ^ ((r & 7) << 4)));
      }
  };
  auto LDB_ = [&](int buf, int qn, bf16x8 (*bb)[2]) {
#pragma unroll
    for (int nf = 0; nf < 2; ++nf)
#pragma unroll
      for (int kk = 0; kk < 2; ++kk) {
        int r = nf * 64 + wn16 + l15;
        int lb = r * 128 + kk * 64 + l4 * 16;
        bb[nf][kk] = *(const bf16x8*)((char*)SMEM + 65536 + buf * 32768 +
                                      qn * 16384 + (lb ^ ((r & 7) << 4)));
      }
  };

  const int NT = K >> 6;
  STAGE(0, 0, 0, 0); STAGE(0, 0, 1, 0); STAGE(0, 1, 1, 0); STAGE(0, 1, 0, 0);
  STAGE(1, 0, 0, 1); STAGE(1, 0, 1, 1);
  asm volatile("s_waitcnt vmcnt(4)" ::: "memory");
  __builtin_amdgcn_s_barrier();

  for (int t = 0; t < NT; ++t) {
    const int cb = t & 1;
    if (t + 1 < NT) STAGE(cb ^ 1, 1, 1, t + 1);
    LDA_(cb, 0);
    LDB_(cb, 0, b0);
    __builtin_amdgcn_s_barrier();
    asm volatile("s_waitcnt lgkmcnt(0)" ::: "memory");
    __builtin_amdgcn_sched_barrier(0);
    MM_PHASE(0, 0, b0);
    __builtin_amdgcn_s_barrier();
    if (t + 1 < NT) STAGE(cb ^ 1, 1, 0, t + 1);
    LDB_(cb, 1, b1);
    __builtin_amdgcn_s_barrier();
    asm volatile("s_waitcnt lgkmcnt(0)" ::: "memory");
    __builtin_amdgcn_sched_barrier(0);
    MM_PHASE(0, 1, b1);
    __builtin_amdgcn_s_barrier();
    if (t + 2 < NT) STAGE(cb, 0, 0, t + 2);
    LDA_(cb, 1);
    __builtin_amdgcn_s_barrier();
    asm volatile("s_waitcnt lgkmcnt(0)" ::: "memory");
    __builtin_amdgcn_sched_barrier(0);
    MM_PHASE(1, 0, b0);
    __builtin_amdgcn_s_barrier();
    if (t + 2 < NT) STAGE(cb, 0, 1, t + 2);
    __builtin_amdgcn_s_barrier();
    MM_PHASE(1, 1, b1);
    if (t + 2 < NT) asm volatile("s_waitcnt vmcnt(4)" ::: "memory");
    else            asm volatile("s_waitcnt vmcnt(0)" ::: "memory");
    __builtin_amdgcn_s_barrier();
  }

#pragma unroll
  for (int mfg = 0; mfg < 8; ++mfg)
#pragma unroll
    for (int nfg = 0; nfg < 4; ++nfg)
#pragma unroll
      for (int r = 0; r < 4; ++r) {
        long row = bm + mfg * 32 + wm16 + l4 * 4 + r;
        long col = bn + nfg * 64 + wn16 + l15;
        float v = acc[mfg][nfg][r];
        if constexpr (MODE == 0) {
          ((u16*)Cv)[row * ldc + col] = f2bf(v);
        } else if constexpr (MODE == 1) {
          ((float*)Cv)[row * ldc + col] = v;
        } else {
          int h = (int)(col >> 8), c = (int)(col & 255);
          if (c < 128)
            ((u16*)Cv)[(((row >> 11) * 16 + h) * 2048 + (row & 2047)) * 128 + c] = f2bf(v);
          else
            Vc[row * 2048 + h * 128 + (c - 128)] = f2bf(v);
        }
      }
}

// ---------------- 256x128 4-phase NT GEMM (tall variant, 96KB LDS) ----------------
#define MM_TALL(QM, QN, BB)                                                      \
  __builtin_amdgcn_s_setprio(1);                                                 \
  {                                                                              \
    _Pragma("unroll") for (int mf = 0; mf < 4; ++mf) {                           \
      _Pragma("unroll") for (int kk = 0; kk < 2; ++kk) {                         \
        acc[(QM) * 4 + mf][(QN)] = __builtin_amdgcn_mfma_f32_16x16x32_bf16(      \
            a[mf][kk], BB[kk], acc[(QM) * 4 + mf][(QN)], 0, 0, 0);               \
      }                                                                          \
    }                                                                            \
  }                                                                              \
  __builtin_amdgcn_s_setprio(0);

template <int MODE>
__global__ __launch_bounds__(512, 2) void gemm_tall(const u16* __restrict__ A, int lda,
                                                    const u16* __restrict__ B, int ldb,
                                                    void* __restrict__ Cv, int ldc,
                                                    u16* __restrict__ Vc, int K) {
  __shared__ u16 SMEM[49152];  // 96 KB: A 64KB | B 32KB
  const int tid = threadIdx.x;
  const int lane = tid & 63, wid = tid >> 6;
  const int l15 = lane & 15, l4 = lane >> 4;
  const int wm16 = (wid >> 2) * 16, wn16 = (wid & 3) * 16;

  const int gx = gridDim.x, nwg = gx * gridDim.y;
  int lin0 = blockIdx.y * gx + blockIdx.x;
  int cpx = nwg >> 3;
  int swzb = (lin0 & 7) * cpx + (lin0 >> 3);
  const long bm = (long)(swzb / gx) * 256;
  const long bn = (long)(swzb % gx) * 128;

  long aoff[2], boffv;
#pragma unroll
  for (int j = 0; j < 2; ++j) {
    int lb = (j * 512 + tid) * 16;
    int swz = lb ^ (((lb >> 7) & 7) << 4);
    aoff[j] = (bm + (swz >> 7)) * (long)lda + ((swz & 127) >> 1);
  }
  {
    int lb = tid * 16;
    int swz = lb ^ (((lb >> 7) & 7) << 4);
    boffv = (bn + (swz >> 7)) * (long)ldb + ((swz & 127) >> 1);
  }

  auto SA = [&](int buf, int half, int tt) {
#pragma unroll
    for (int j = 0; j < 2; ++j)
      __builtin_amdgcn_global_load_lds(
          (const GLV*)(A + aoff[j] + (long)half * 128 * lda + tt * 64),
          (LDSV*)((char*)SMEM + buf * 32768 + half * 16384 + (j * 512 + tid) * 16),
          16, 0, 0);
  };
  auto SB = [&](int buf, int half, int tt) {
    __builtin_amdgcn_global_load_lds(
        (const GLV*)(B + boffv + (long)half * 64 * ldb + tt * 64),
        (LDSV*)((char*)SMEM + 65536 + buf * 16384 + half * 8192 + tid * 16),
        16, 0, 0);
  };

  f32x4 acc[8][2] = {};
  bf16x8 a[4][2], b0[2], b1[2];

  auto LDA_ = [&](int buf, int qm) {
#pragma unroll
    for (int mf = 0; mf < 4; ++mf)
#pragma unroll
      for (int kk = 0; kk < 2; ++kk) {
        int r = mf * 32 + wm16 + l15;
        int lb = r * 128 + kk * 64 + l4 * 16;
        a[mf][kk] = *(const bf16x8*)((char*)SMEM + buf * 32768 + qm * 16384 +
                                     (lb ^ ((r & 7) << 4)));
      }
  };
  auto LDB_ = [&](int buf, int qn, bf16x8* bb) {
#pragma unroll
    for (int kk = 0; kk < 2; ++kk) {
      int r = wn16 + l15;
      int lb = r * 128 + kk * 64 + l4 * 16;
      bb[kk] = *(const bf16x8*)((char*)SMEM + 65536 + buf * 16384 + qn * 8192 +
                                (lb ^ ((r & 7) << 4)));
    }
  };

  const int NT = K >> 6;
  SA(0, 0, 0); SB(0, 0, 0); SB(0, 1, 0); SA(0, 1, 0);
  SA(1, 0, 1); SB(1, 0, 1);
  asm volatile("s_waitcnt vmcnt(3)" ::: "memory");
  __builtin_amdgcn_s_barrier();

  for (int t = 0; t < NT; ++t) {
    const int cb = t & 1;
    if (t + 1 < NT) SB(cb ^ 1, 1, t + 1);
    LDA_(cb, 0);
    LDB_(cb, 0, b0);
    __builtin_amdgcn_s_barrier();
    asm volatile("s_waitcnt lgkmcnt(0)" ::: "memory");
    __builtin_amdgcn_sched_barrier(0);
    MM_TALL(0, 0, b0);
    __builtin_amdgcn_s_barrier();
    if (t + 1 < NT) SA(cb ^ 1, 1, t + 1);
    LDB_(cb, 1, b1);
    __builtin_amdgcn_s_barrier();
    asm volatile("s_waitcnt lgkmcnt(0)" ::: "memory");
    __builtin_amdgcn_sched_barrier(0);
    MM_TALL(0, 1, b1);
    __builtin_amdgcn_s_barrier();
    if (t + 2 < NT) SA(cb, 0, t + 2);
    LDA_(cb, 1);
    __builtin_amdgcn_s_barrier();
    asm volatile("s_waitcnt lgkmcnt(0)" ::: "memory");
    __builtin_amdgcn_sched_barrier(0);
    MM_TALL(1, 0, b0);
    __builtin_amdgcn_s_barrier();
    if (t + 2 < NT) SB(cb, 0, t + 2);
    __builtin_amdgcn_s_barrier();
    MM_TALL(1, 1, b1);
    if (t + 2 < NT) asm volatile("s_waitcnt vmcnt(6)" ::: "memory");
    else            asm volatile("s_waitcnt vmcnt(0)" ::: "memory");
    __builtin_amdgcn_s_barrier();
  }

#pragma unroll
  for (int mfg = 0; mfg < 8; ++mfg)
#pragma unroll
    for (int qn = 0; qn < 2; ++qn)
#pragma unroll
      for (int r = 0; r < 4; ++r) {
        long row = bm + mfg * 32 + wm16 + l4 * 4 + r;
        long col = bn + qn * 64 + wn16 + l15;
        float v = acc[mfg][qn][r];
        if constexpr (MODE == 0) {
          ((u16*)Cv)[row * ldc + col] = f2bf(v);
        } else if constexpr (MODE == 1) {
          ((float*)Cv)[row * ldc + col] = v;
        } else {
          int h = (int)(col >> 8), c = (int)(col & 255);
          if (c < 128)
            ((u16*)Cv)[(((row >> 11) * 16 + h) * 2048 + (row & 2047)) * 128 + c] = f2bf(v);
          else
            Vc[row * 2048 + h * 128 + (c - 128)] = f2bf(v);
        }
      }
}

// ---------------- both RMSNorms in one dispatch ----------------
__global__ __launch_bounds__(256) void rmsnorm2_kernel(u16* __restrict__ qakv,
                                                       const float* __restrict__ qw,
                                                       const float* __restrict__ kvw) {
  __shared__ float sred[4];
  const int tid = threadIdx.x;
  const int row = blockIdx.x;
  if (row < 4096) {
    u16* p = qakv + (size_t)row * 1408;
    float x[3];
    float ss = 0.f;
#pragma unroll
    for (int i = 0; i < 3; ++i) { x[i] = bf2f(p[tid + i * 256]); ss += x[i] * x[i]; }
#pragma unroll
    for (int off = 1; off < 64; off <<= 1) ss += __shfl_xor(ss, off);
    if ((tid & 63) == 0) sred[tid >> 6] = ss;
    __syncthreads();
    float tot = sred[0] + sred[1] + sred[2] + sred[3];
    float rs = rsqrtf(tot * (1.0f / 768.0f) + 1e-6f) * 0.0069411711f;  // SCALE*log2e/15
#pragma unroll
    for (int i = 0; i < 3; ++i) p[tid + i * 256] = f2bf(x[i] * rs * qw[tid + i * 256]);
  } else {
    u16* p = qakv + (size_t)(row - 4096) * 1408 + 768;
    float x[2];
    float ss = 0.f;
#pragma unroll
    for (int i = 0; i < 2; ++i) { x[i] = bf2f(p[tid + i * 256]); ss += x[i] * x[i]; }
#pragma unroll
    for (int off = 1; off < 64; off <<= 1) ss += __shfl_xor(ss, off);
    if ((tid & 63) == 0) sred[tid >> 6] = ss;
    __syncthreads();
    float tot = sred[0] + sred[1] + sred[2] + sred[3];
    float rs = rsqrtf(tot * (1.0f / 512.0f) + 1e-6f);
#pragma unroll
    for (int i = 0; i < 2; ++i) p[tid + i * 256] = f2bf(x[i] * rs * kvw[tid + i * 256]);
  }
}

// ---------------- RoPE on k_pe -> compact kpe [b*S][64] ----------------
__global__ __launch_bounds__(256) void ropek_kernel(const u16* __restrict__ qakv,
                                                    const float* __restrict__ cosb,
                                                    const float* __restrict__ sinb,
                                                    u16* __restrict__ kpe) {
  int idx = blockIdx.x * 256 + threadIdx.x;
  int i = idx & 31;
  int srow = idx >> 5;
  int s = srow & 2047;
  unsigned int v = *(const unsigned int*)(qakv + (size_t)srow * 1408 + 1280 + 2 * i);
  float xe = bf2f((u16)(v & 0xffff)), xo = bf2f((u16)(v >> 16));
  float c = cosb[s * 32 + i], sn = sinb[s * 32 + i];
  *(unsigned int*)(kpe + (size_t)srow * 64 + 2 * i) =
      (unsigned int)f2bf(xe * c - xo * sn) | ((unsigned int)f2bf(xe * sn + xo * c) << 16);
}

// ---------------- V transpose: VT [B*H][128][S] from Vc [B*S][2048] ----------------
__global__ __launch_bounds__(256) void v_transpose_kernel(const u16* __restrict__ Vc,
                                                          u16* __restrict__ VT) {
  __shared__ u16 tile[64][65];
  int bh = blockIdx.z;
  int d0 = blockIdx.y * 64;
  int t0 = blockIdx.x * 64;
  int b = bh >> 4, h = bh & 15;
#pragma unroll
  for (int i = 0; i < 2; ++i) {
    int flat = i * 256 + threadIdx.x;
    int t = flat >> 3, c = (flat & 7) * 8;
    u32x4 v = *(const u32x4*)(Vc + ((long)b * S_LEN + t0 + t) * 2048 + h * 128 + d0 + c);
    const u16* pv = (const u16*)&v;
#pragma unroll
    for (int j = 0; j < 8; ++j) tile[c + j][t] = pv[j];
  }
  __syncthreads();
#pragma unroll
  for (int i = 0; i < 2; ++i) {
    int flat = i * 256 + threadIdx.x;
    int d = flat >> 3, tc = (flat & 7) * 8;
    u32x4 v;
    u16* pv = (u16*)&v;
#pragma unroll
    for (int j = 0; j < 8; ++j) pv[j] = tile[d][tc + j];
    *(u32x4*)(VT + ((long)bh * 128 + d0 + d) * S_LEN + t0 + tc) = v;
  }
}

// ---------------- fused causal attention + softcap + v-projection removal ----------
// 8 waves, QT=128, KT=64, double-buffered K/V LDS -> ONE barrier per k-tile.
// RoPE on Q applied at fragment load (pairs are in-lane for f=4,5). Fixed softmax
// ref m=30. Paired q-tiles (qt,15-qt). XCD swizzle. Swapped QK -> cvt_pk P path.
__global__ __launch_bounds__(512, 2) void attn_kernel(const u16* __restrict__ Qg,
                                                      const u16* __restrict__ KbN,
                                                      const u16* __restrict__ Kpe,
                                                      const u16* __restrict__ VTg,
                                                      const u16* __restrict__ Vcg,
                                                      const float* __restrict__ cosb,
                                                      const float* __restrict__ sinb,
                                                      const float* __restrict__ gain,
                                                      u16* __restrict__ Yg) {
  __shared__ u16 Ks[2][64 * 192];   // 48KB
  __shared__ u16 VTs[2][128 * 64];  // 32KB
  __shared__ u16 Ps[128 * 64];      // 16KB (wave-private rows)

  const int tid = threadIdx.x, lane = tid & 63, wid = tid >> 6;
  const int l15 = lane & 15, l4 = lane >> 4;

  const int p = blockIdx.x;               // 256 blocks
  const int bh = (p & 7) * 4 + (p >> 6);  // same-bh blocks share an XCD
  const int pair = (p >> 3) & 7;
  const int b = bh >> 4, h = bh & 15;

  const u16* Kn = KbN + (long)bh * S_LEN * 128;
  const u16* Kp = Kpe + (long)b * S_LEN * 64;
  const u16* Vbh = VTg + (long)bh * 128 * S_LEN;

  int krow[3], sst[3], ksoff[3];
  const u16* sb[3];
#pragma unroll
  for (int i = 0; i < 3; ++i) {
    int flat = i * 512 + tid;
    int r = flat / 24, c = flat % 24;
    krow[i] = r;
    if (c < 16) { sb[i] = Kn + c * 8; sst[i] = 128; }
    else        { sb[i] = Kp + (c - 16) * 8; sst[i] = 64; }
    ksoff[i] = r * 192 + ((c ^ (r & 7)) * 8);
  }
  int vrow[2], vc[2], vsoff[2];
#pragma unroll
  for (int i = 0; i < 2; ++i) {
    int flat = i * 512 + tid;
    vrow[i] = flat >> 3; vc[i] = flat & 7;
    vsoff[i] = vrow[i] * 64 + ((vc[i] ^ (vrow[i] & 7)) * 8);
  }

  const int prow = wid * 16 + l15;
  const int pr7 = prow & 7;
  const float g = gain[h];

  for (int seg = 0; seg < 2; ++seg) {
    const int qt = seg ? pair : 15 - pair;
    const int q0 = qt * 128;
    const int nkt = 2 * qt + 2;
    const int sq = q0 + prow;

    bf16x8 qf[6];
    {
      const u16* qb_ = Qg + ((long)b * S_LEN + sq) * 3072 + h * 192;
#pragma unroll
      for (int f = 0; f < 6; ++f) qf[f] = *(const bf16x8*)(qb_ + f * 32 + 8 * l4);
    }
    // RoPE + gain on q_pe fragments (f=4,5): pairs are in-lane
#pragma unroll
    for (int f = 4; f < 6; ++f) {
      float4 cv = *(const float4*)(cosb + sq * 32 + (f - 4) * 16 + l4 * 4);
      float4 sv = *(const float4*)(sinb + sq * 32 + (f - 4) * 16 + l4 * 4);
      float cc[4] = {cv.x, cv.y, cv.z, cv.w};
      float ssn[4] = {sv.x, sv.y, sv.z, sv.w};
      u16* pq = (u16*)&qf[f];
#pragma unroll
      for (int pp = 0; pp < 4; ++pp) {
        float xe = bf2f(pq[2 * pp]), xo = bf2f(pq[2 * pp + 1]);
        pq[2 * pp]     = f2bf((xe * cc[pp] - xo * ssn[pp]) * g);
        pq[2 * pp + 1] = f2bf((xe * ssn[pp] + xo * cc[pp]) * g);
      }
    }

    f32x4 o[8] = {};
    float lsum = 0.f;

    u32x4 ka[3], va[2];
    // prologue: tile 0 -> LDS[0]; prefetch tile 1 into regs
#pragma unroll
    for (int i = 0; i < 3; ++i)
      ka[i] = *(const u32x4*)(sb[i] + (long)krow[i] * sst[i]);
#pragma unroll
    for (int i = 0; i < 2; ++i)
      va[i] = *(const u32x4*)(Vbh + (long)vrow[i] * S_LEN + vc[i] * 8);
#pragma unroll
    for (int i = 0; i < 3; ++i) *(u32x4*)(&Ks[0][ksoff[i]]) = ka[i];
#pragma unroll
    for (int i = 0; i < 2; ++i) *(u32x4*)(&VTs[0][vsoff[i]]) = va[i];
    if (nkt > 1) {
#pragma unroll
      for (int i = 0; i < 3; ++i)
        ka[i] = *(const u32x4*)(sb[i] + (long)(64 + krow[i]) * sst[i]);
#pragma unroll
      for (int i = 0; i < 2; ++i)
        va[i] = *(const u32x4*)(Vbh + (long)vrow[i] * S_LEN + 64 + vc[i] * 8);
    }
    __syncthreads();

    for (int it = 0; it < nkt; ++it) {
      const int cur = it & 1;

      f32x4 sacc[4] = {};
      __builtin_amdgcn_s_setprio(1);
#pragma unroll
      for (int f = 0; f < 6; ++f)
#pragma unroll
        for (int tf = 0; tf < 4; ++tf) {
          int row = tf * 16 + l15;
          bf16x8 kf = *(const bf16x8*)(&Ks[cur][row * 192 + (((f * 4 + l4) ^ (row & 7)) * 8)]);
          sacc[tf] = __builtin_amdgcn_mfma_f32_16x16x32_bf16(kf, qf[f], sacc[tf], 0, 0, 0);
        }
      __builtin_amdgcn_s_setprio(0);

      // stage next tile into other buffer; prefetch t+2 into regs
      if (it + 1 < nkt) {
#pragma unroll
        for (int i = 0; i < 3; ++i) *(u32x4*)(&Ks[cur ^ 1][ksoff[i]]) = ka[i];
#pragma unroll
        for (int i = 0; i < 2; ++i) *(u32x4*)(&VTs[cur ^ 1][vsoff[i]]) = va[i];
      }
      if (it + 2 < nkt) {
        int k0n = (it + 2) * 64;
#pragma unroll
        for (int i = 0; i < 3; ++i)
          ka[i] = *(const u32x4*)(sb[i] + (long)(k0n + krow[i]) * sst[i]);
#pragma unroll
        for (int i = 0; i < 2; ++i)
          va[i] = *(const u32x4*)(Vbh + (long)vrow[i] * S_LEN + k0n + vc[i] * 8);
      }

      // softmax with fixed reference (q pre-scaled in rmsnorm)
#pragma unroll
      for (int tf = 0; tf < 4; ++tf)
#pragma unroll
        for (int r = 0; r < 4; ++r) {
          float u = __builtin_amdgcn_exp2f(sacc[tf][r]);
          sacc[tf][r] = __builtin_amdgcn_exp2f(-86.56170245333781f *
                                               __builtin_amdgcn_rcpf(u + 1.0f));
        }
      if (it * 64 >= q0) {  // causal: kpos > qrow -> 0
        const int dthr = q0 + prow - it * 64 - l4 * 4;
#pragma unroll
        for (int tf = 0; tf < 4; ++tf)
#pragma unroll
          for (int r = 0; r < 4; ++r)
            if (tf * 16 + r > dthr) sacc[tf][r] = 0.f;
      }
#pragma unroll
      for (int tf = 0; tf < 4; ++tf)
#pragma unroll
        for (int r = 0; r < 4; ++r) lsum += sacc[tf][r];

#pragma unroll
      for (int tf = 0; tf < 4; ++tf) {
        u32x2 w;
        w.x = cvtpk(sacc[tf][0], sacc[tf][1]);
        w.y = cvtpk(sacc[tf][2], sacc[tf][3]);
        int chunk = tf * 2 + (l4 >> 1);
        *(u32x2*)(&Ps[prow * 64 + ((chunk ^ pr7) * 8) + (l4 & 1) * 4]) = w;
      }

      __builtin_amdgcn_s_setprio(1);
#pragma unroll
      for (int kk = 0; kk < 2; ++kk) {
        bf16x8 pf = *(const bf16x8*)(&Ps[prow * 64 + (((kk * 4 + l4) ^ pr7) * 8)]);
#pragma unroll
        for (int nf = 0; nf < 8; ++nf) {
          int vr = nf * 16 + l15;
          bf16x8 vf = *(const bf16x8*)(&VTs[cur][vr * 64 + (((kk * 4 + l4) ^ (vr & 7)) * 8)]);
          o[nf] = __builtin_amdgcn_mfma_f32_16x16x32_bf16(pf, vf, o[nf], 0, 0, 0);
        }
      }
      __builtin_amdgcn_s_setprio(0);

      __syncthreads();  // single barrier per tile: flip buffers
    }

    lsum += __shfl_xor(lsum, 16);
    lsum += __shfl_xor(lsum, 32);
    float inv[4];
#pragma unroll
    for (int r = 0; r < 4; ++r)
      inv[r] = __builtin_amdgcn_rcpf(__shfl(lsum, l4 * 4 + r));

    float yv[8][4], vvv[8][4];
    float ssum[4] = {0.f, 0.f, 0.f, 0.f}, dsum[4] = {0.f, 0.f, 0.f, 0.f};
    const u16* vb = Vcg + ((long)b * S_LEN + q0 + wid * 16) * 2048 + h * 128;
#pragma unroll
    for (int nf = 0; nf < 8; ++nf)
#pragma unroll
      for (int r = 0; r < 4; ++r) {
        float vv = bf2f(vb[(l4 * 4 + r) * 2048 + nf * 16 + l15]);
        float y = o[nf][r] * inv[r];
        vvv[nf][r] = vv; yv[nf][r] = y;
        ssum[r] += vv * vv; dsum[r] += y * vv;
      }
#pragma unroll
    for (int r = 0; r < 4; ++r) {
      ssum[r] += __shfl_xor(ssum[r], 1); ssum[r] += __shfl_xor(ssum[r], 2);
      ssum[r] += __shfl_xor(ssum[r], 4); ssum[r] += __shfl_xor(ssum[r], 8);
      dsum[r] += __shfl_xor(dsum[r], 1); dsum[r] += __shfl_xor(dsum[r], 2);
      dsum[r] += __shfl_xor(dsum[r], 4); dsum[r] += __shfl_xor(dsum[r], 8);
      dsum[r] *= __builtin_amdgcn_rcpf(fmaxf(ssum[r], 1e-12f));
    }
#pragma unroll
    for (int nf = 0; nf < 8; ++nf)
#pragma unroll
      for (int r = 0; r < 4; ++r) {
        long row = (long)b * S_LEN + q0 + wid * 16 + l4 * 4 + r;
        Yg[row * 2048 + h * 128 + nf * 16 + l15] = f2bf(yv[nf][r] - dsum[r] * vvv[nf][r]);
      }
  }
}

extern "C" void kernel_launch(void* const* d_in, const int* in_sizes, int n_in,
                              void* d_out, int out_size, void* d_ws, size_t ws_size,
                              hipStream_t stream) {
  const float* x       = (const float*)d_in[0];
  const float* wq_a    = (const float*)d_in[1];
  const float* q_norm  = (const float*)d_in[2];
  const float* wq_b    = (const float*)d_in[3];
  const float* q_gain  = (const float*)d_in[4];
  const float* wkv_a   = (const float*)d_in[5];
  const float* kv_norm = (const float*)d_in[6];
  const float* wkv_b   = (const float*)d_in[7];
  const float* wo      = (const float*)d_in[8];
  const float* fcos    = (const float*)d_in[9];
  const float* fsin    = (const float*)d_in[10];
  float* out = (float*)d_out;

  char* ws = (char*)d_ws;
  size_t off = 0;
  auto alloc = [&](size_t bytes) {
    char* pp = ws + off;
    off += (bytes + 255) & ~(size_t)255;
    return pp;
  };
  const long M = 4096;  // B*S
  u16* xb    = (u16*)alloc(M * 2048 * 2);
  u16* wcomb = (u16*)alloc(1408L * 2048 * 2);
  u16* wqbb  = (u16*)alloc(3072L * 768 * 2);
  u16* wkvbb = (u16*)alloc(4096L * 512 * 2);
  u16* wob   = (u16*)alloc(2048L * 2048 * 2);
  u16* qakv  = (u16*)alloc(M * 1408 * 2);
  u16* qb    = (u16*)alloc(M * 3072 * 2);
  u16* KbN   = (u16*)alloc(32L * 2048 * 128 * 2);
  u16* kpe   = (u16*)alloc(M * 64 * 2);
  u16* Vc    = (u16*)alloc(M * 2048 * 2);
  u16* VTb   = (u16*)alloc(32L * 128 * 2048 * 2);
  u16* Yb    = (u16*)alloc(M * 2048 * 2);

  const long n4_x = 2097152, n4_wqa = 393216, n4_wqb = 589824,
             n4_wkvb = 524288, n4_wo = 1048576, n4_wkvap = 327680;
  long e0 = n4_x, e1 = e0 + n4_wqa, e2 = e1 + n4_wqb, e3 = e2 + n4_wkvb,
       e4 = e3 + n4_wo, e5 = e4 + n4_wkvap;
  cast_all<<<(int)(e5 / 256), 256, 0, stream>>>(
      x, xb, e0, wq_a, wcomb, e1, wq_b, wqbb, e2, wkv_b, wkvbb, e3,
      wo, wob, e4, wkv_a, wcomb + 768L * 2048, e5);

  // fused: [q_a | kv_full] = x @ [wq_a; wkv_a]^T   (N=1408, 256x128 tall)
  gemm_tall<0><<<dim3(11, 16), 512, 0, stream>>>(xb, 2048, wcomb, 2048, qakv, 1408, nullptr, 2048);
  rmsnorm2_kernel<<<8192, 256, 0, stream>>>(qakv, q_norm, kv_norm);
  // q = q_a @ wq_b^T  (8-phase 256^2) -- RoPE applied later inside attn
  gemm256<0><<<dim3(12, 16), 512, 0, stream>>>(qakv, 1408, wqbb, 768, qb, 3072, nullptr, 768);
  ropek_kernel<<<131072 / 256, 256, 0, stream>>>(qakv, fcos, fsin, kpe);
  // kvb = kv @ wkv_b^T, split epilogue  (8-phase 256^2)
  gemm256<2><<<dim3(16, 16), 512, 0, stream>>>(qakv + 768, 1408, wkvbb, 512, KbN, 0, Vc, 512);
  v_transpose_kernel<<<dim3(32, 2, 32), 256, 0, stream>>>(Vc, VTb);
  attn_kernel<<<256, 512, 0, stream>>>(qb, KbN, kpe, VTb, Vc, fcos, fsin, q_gain, Yb);
  // out = y @ wo^T (f32 out)  (256x128 tall)
  gemm_tall<1><<<dim3(16, 16), 512, 0, stream>>>(Yb, 2048, wob, 2048, out, 2048, nullptr, 2048);
}